// Round 5
// baseline (169.671 us; speedup 1.0000x reference)
//
#include <hip/hip_runtime.h>

typedef short s16x4 __attribute__((ext_vector_type(4)));
typedef short s16x8 __attribute__((ext_vector_type(8)));
typedef float f32x4 __attribute__((ext_vector_type(4)));
typedef unsigned int u32;

#define DEV static __device__ __forceinline__

// B=4, S=2048, D=512, H=8, DK=64, M = B*S = 8192

DEV unsigned short f2bf(float f) {
    unsigned u = __float_as_uint(f);
    u += 0x7FFFu + ((u >> 16) & 1u);   // RNE round to bf16
    return (unsigned short)(u >> 16);
}

DEV u32 cvtpk(float lo, float hi) {
    u32 r;
    asm("v_cvt_pk_bf16_f32 %0, %1, %2" : "=v"(r) : "v"(lo), "v"(hi));
    return r;
}
DEV void pl32swap(u32& a, u32& b) {
    asm("v_permlane32_swap_b32 %0, %1" : "+v"(a), "+v"(b));
}
DEV void pl16swap(u32& a, u32& b) {
    asm("v_permlane16_swap_b32 %0, %1" : "+v"(a), "+v"(b));
}
DEV void gl16(const void* g, void* l) {
    __builtin_amdgcn_global_load_lds((const __attribute__((address_space(1))) u32*)g,
                                     (__attribute__((address_space(3))) u32*)l, 16, 0, 0);
}

// ---------------- fused LayerNorm + weight convert ----------------
// blocks [0,2048): LN rows; blocks [2048,2304): weight fp32->bf16
__global__ __launch_bounds__(256) void lnw_kernel(const float* __restrict__ x,
        const float* __restrict__ gamma, const float* __restrict__ beta,
        unsigned short* __restrict__ xn,
        const float* __restrict__ wq, const float* __restrict__ wk,
        const float* __restrict__ wv, const float* __restrict__ wo,
        unsigned short* __restrict__ wdst)
{
    if (blockIdx.x >= 2048) {
        int idx = blockIdx.x - 2048;
        int m = idx >> 6, sub = idx & 63;
        const float* src = (m == 0) ? wq : (m == 1) ? wk : (m == 2) ? wv : wo;
        unsigned short* d = wdst + (size_t)m * 262144;
        const f32x4* s4 = (const f32x4*)src;
        s16x4* d4 = (s16x4*)d;
#pragma unroll
        for (int i = 0; i < 4; ++i) {
            int e = sub * 1024 + i * 256 + threadIdx.x;
            f32x4 v = s4[e];
            s16x4 o;
            o[0] = f2bf(v[0]); o[1] = f2bf(v[1]); o[2] = f2bf(v[2]); o[3] = f2bf(v[3]);
            d4[e] = o;
        }
        return;
    }
    int t = threadIdx.x, w = t >> 6, lane = t & 63;
    int row = blockIdx.x * 4 + w;
    const float* xr = x + (size_t)row * 512 + lane * 8;
    f32x4 v0 = *(const f32x4*)xr;
    f32x4 v1 = *(const f32x4*)(xr + 4);
    float s = 0.f, s2 = 0.f;
#pragma unroll
    for (int i = 0; i < 4; ++i) { s += v0[i] + v1[i]; s2 += v0[i] * v0[i] + v1[i] * v1[i]; }
#pragma unroll
    for (int m = 1; m < 64; m <<= 1) { s += __shfl_xor(s, m); s2 += __shfl_xor(s2, m); }
    float mu = s * (1.f / 512.f);
    float var = s2 * (1.f / 512.f) - mu * mu;
    float rstd = rsqrtf(var + 1e-5f);
    f32x4 g0 = *(const f32x4*)(gamma + lane * 8);
    f32x4 g1 = *(const f32x4*)(gamma + lane * 8 + 4);
    f32x4 b0 = *(const f32x4*)(beta + lane * 8);
    f32x4 b1 = *(const f32x4*)(beta + lane * 8 + 4);
    s16x8 o;
#pragma unroll
    for (int i = 0; i < 4; ++i) {
        o[i]     = f2bf((v0[i] - mu) * rstd * g0[i] + b0[i]);
        o[i + 4] = f2bf((v1[i] - mu) * rstd * g1[i] + b1[i]);
    }
    *(s16x8*)(xn + (size_t)row * 512 + lane * 8) = o;
}

// ---------------- QKV projection GEMM (gl16 + pre-swizzled source + swizzled reads) ----------------
// z=0 -> q (b,h,s,dk) scaled 0.125*log2e ; z=1 -> k (b,h,s,dk) ; z=2 -> v^T (b,h,dk,s)
__global__ __launch_bounds__(256) void qkv_kernel(const unsigned short* __restrict__ xn,
        const unsigned short* __restrict__ wbase,
        const float* __restrict__ bq, const float* __restrict__ bk, const float* __restrict__ bv,
        unsigned short* __restrict__ qo, unsigned short* __restrict__ ko,
        unsigned short* __restrict__ vt)
{
    __shared__ __align__(16) unsigned short As[128 * 64];
    __shared__ __align__(16) unsigned short Bs[128 * 64];
    int z = blockIdx.z;
    const unsigned short* W = wbase + (size_t)z * 262144;
    const float* bias = (z == 0) ? bq : (z == 1) ? bk : bv;

    int t = threadIdx.x, lane = t & 63, w = t >> 6;
    int g = lane >> 4, l15 = lane & 15;
    int wm = w >> 1, wn = w & 1;
    int mBase = blockIdx.x * 128, nBase = blockIdx.y * 128;

    int srow = t >> 3;                               // 32 rows per 4KB chunk
    int scol = (((t & 7) ^ (srow & 7))) * 8;         // pre-swizzled source col (elems)
    const unsigned short* ag = xn + (size_t)(mBase + srow) * 512 + scol;
    const unsigned short* bg = W + (size_t)(nBase + srow) * 512 + scol;
    char* al = (char*)As + t * 16;
    char* bl = (char*)Bs + t * 16;

    f32x4 acc[4][4] = {};

    for (int k0 = 0; k0 < 512; k0 += 64) {
        __syncthreads();
#pragma unroll
        for (int i = 0; i < 4; ++i) {                // rows +32i: (row&7) unchanged
            gl16(ag + (size_t)i * 16384 + k0, al + i * 4096);
            gl16(bg + (size_t)i * 16384 + k0, bl + i * 4096);
        }
        __syncthreads();
#pragma unroll
        for (int ks = 0; ks < 2; ++ks) {
            s16x8 af[4], bf[4];
#pragma unroll
            for (int i = 0; i < 4; ++i) {
                int ar = wm * 64 + i * 16 + l15;
                af[i] = *(const s16x8*)((const char*)As + ar * 128 + ((ks * 64 + g * 16) ^ ((ar & 7) << 4)));
                int br = wn * 64 + i * 16 + l15;
                bf[i] = *(const s16x8*)((const char*)Bs + br * 128 + ((ks * 64 + g * 16) ^ ((br & 7) << 4)));
            }
            __builtin_amdgcn_s_setprio(1);
#pragma unroll
            for (int i = 0; i < 4; ++i)
#pragma unroll
                for (int j = 0; j < 4; ++j)
                    acc[i][j] = __builtin_amdgcn_mfma_f32_16x16x32_bf16(af[i], bf[j], acc[i][j], 0, 0, 0);
            __builtin_amdgcn_s_setprio(0);
        }
    }

#pragma unroll
    for (int i = 0; i < 4; ++i) {
        int row0 = mBase + wm * 64 + i * 16 + g * 4;
        int bb = row0 >> 11;
        int s0 = row0 & 2047;
#pragma unroll
        for (int j = 0; j < 4; ++j) {
            int col = nBase + wn * 64 + j * 16 + l15;
            float bia = bias[col];
            int h = col >> 6, dk = col & 63;
            if (z == 2) {
                s16x4 pk;
#pragma unroll
                for (int r = 0; r < 4; ++r) pk[r] = f2bf(acc[i][j][r] + bia);
                *(s16x4*)(vt + ((size_t)(bb * 8 + h) * 64 + dk) * 2048 + s0) = pk;
            } else {
                unsigned short* dst = (z == 0) ? qo : ko;
                // q scale folds 1/sqrt(DK) AND log2(e) so attn uses exp2 directly
                float sc = (z == 0) ? 0.18033688011112042f : 1.0f;
#pragma unroll
                for (int r = 0; r < 4; ++r)
                    dst[((size_t)(bb * 8 + h) * 2048 + (s0 + r)) * 64 + dk] = f2bf((acc[i][j][r] + bia) * sc);
            }
        }
    }
}

// ---------------- flash attention: LDS-free, barrier-free, reg-prefetched ----------------
struct kvreg { s16x8 ka[2][2]; s16x8 vb[4]; };

DEV void kv_load(const unsigned short* __restrict__ kbh, const unsigned short* __restrict__ vbh,
                 int kb, int l15, int g, kvreg& R)
{
    const unsigned short* kp = kbh + (size_t)kb * 64;
#pragma unroll
    for (int kf = 0; kf < 2; ++kf)
#pragma unroll
        for (int ks = 0; ks < 2; ++ks)
            R.ka[kf][ks] = *(const s16x8*)(kp + (kf * 16 + l15) * 64 + ks * 32 + g * 8);
    const unsigned short* vp = vbh + kb + g * 8;
#pragma unroll
    for (int nf = 0; nf < 4; ++nf)
        R.vb[nf] = *(const s16x8*)(vp + (size_t)(nf * 16 + l15) * 2048);
}

DEV void tile_compute(int kb, int len, int g, int l15,
                      const s16x8 (&qf_)[2][2], s16x8 ones, const kvreg& R,
                      f32x4 (&oacc)[2][4], f32x4 (&sacc)[2])
{
    // QK^T -> S^T: sa[kf][qf]; S^T[k = kb+kf*16+g*4+r][q = qf*16+l15]
    f32x4 sa[2][2] = {};
#pragma unroll
    for (int ks = 0; ks < 2; ++ks) {
        __builtin_amdgcn_s_setprio(1);
#pragma unroll
        for (int kf = 0; kf < 2; ++kf)
#pragma unroll
            for (int qf = 0; qf < 2; ++qf)
                sa[kf][qf] = __builtin_amdgcn_mfma_f32_16x16x32_bf16(R.ka[kf][ks], qf_[qf][ks], sa[kf][qf], 0, 0, 0);
        __builtin_amdgcn_s_setprio(0);
    }

    if (kb + 32 > len) {
        const float NEG = -__builtin_huge_valf();
#pragma unroll
        for (int kf = 0; kf < 2; ++kf)
#pragma unroll
            for (int r = 0; r < 4; ++r)
                if (kb + kf * 16 + g * 4 + r >= len) { sa[kf][0][r] = NEG; sa[kf][1][r] = NEG; }
    }

    // fixed-max softmax in log2 domain: P = 2^s (scale folded into q)
    u32 pkd[2][2][2];
#pragma unroll
    for (int qf = 0; qf < 2; ++qf)
#pragma unroll
        for (int kf = 0; kf < 2; ++kf) {
#pragma unroll
            for (int r = 0; r < 4; ++r)
                sa[kf][qf][r] = __builtin_amdgcn_exp2f(sa[kf][qf][r]);
            pkd[kf][qf][0] = cvtpk(sa[kf][qf][0], sa[kf][qf][1]);
            pkd[kf][qf][1] = cvtpk(sa[kf][qf][2], sa[kf][qf][3]);
        }

    // P-fragment via permlane transpose; PV + ones-MFMA row-sum
    __builtin_amdgcn_s_setprio(1);
#pragma unroll
    for (int qf = 0; qf < 2; ++qf) {
        u32 a0 = pkd[0][qf][0], b0 = pkd[1][qf][0];
        u32 a1 = pkd[0][qf][1], b1 = pkd[1][qf][1];
        pl32swap(a0, b0); pl16swap(a0, b0);
        pl32swap(a1, b1); pl16swap(a1, b1);
        union { u32 d[4]; s16x8 v; } pf;
        pf.d[0] = a0; pf.d[1] = a1; pf.d[2] = b0; pf.d[3] = b1;
        sacc[qf] = __builtin_amdgcn_mfma_f32_16x16x32_bf16(pf.v, ones, sacc[qf], 0, 0, 0);
#pragma unroll
        for (int nf = 0; nf < 4; ++nf)
            oacc[qf][nf] = __builtin_amdgcn_mfma_f32_16x16x32_bf16(pf.v, R.vb[nf], oacc[qf][nf], 0, 0, 0);
    }
    __builtin_amdgcn_s_setprio(0);
}

// grid 2048, 64 threads (1 wave). Block mapping: xcd = lin&7 gets bh in
// {xcd*4..xcd*4+3} (L2 clustering); all 8 blocks landing on one CU share bh
// (L1 sharing of identical K/V streams); qi spread over rounds.
__global__ __launch_bounds__(64, 2) void attn_kernel(const unsigned short* __restrict__ q,
        const unsigned short* __restrict__ k, const unsigned short* __restrict__ vt,
        const int* __restrict__ lens, unsigned short* __restrict__ of)
{
    int lane = threadIdx.x & 63;
    int g = lane >> 4, l15 = lane & 15;
    int lin = blockIdx.x;
    int bh = (lin & 7) * 4 + ((lin >> 3) & 3);
    int qi = ((lin >> 5) & 7) + ((lin >> 8) << 3);
    int b = bh >> 3, h = bh & 7;
    int qb = qi * 32;
    int len = lens[b];
    int nt = (len + 31) >> 5;

    const unsigned short* kbh = k + (size_t)bh * 131072;
    const unsigned short* vbh = vt + (size_t)bh * 131072;

    s16x8 qf_[2][2];
#pragma unroll
    for (int qf = 0; qf < 2; ++qf)
#pragma unroll
        for (int ks = 0; ks < 2; ++ks)
            qf_[qf][ks] = *(const s16x8*)(q + ((size_t)bh * 2048 + qb + qf * 16 + l15) * 64 + ks * 32 + g * 8);

    s16x8 ones;
#pragma unroll
    for (int i = 0; i < 8; ++i) ones[i] = (short)0x3F80;   // bf16 1.0

    f32x4 oacc[2][4] = {};
    f32x4 sacc[2] = {};

    kvreg RA, RB;
    kv_load(kbh, vbh, 0, l15, g, RA);

    int tt = 0;
    for (;;) {
        int nkb = ((tt + 1 < nt) ? tt + 1 : nt - 1) << 5;
        kv_load(kbh, vbh, nkb, l15, g, RB);
        tile_compute(tt << 5, len, g, l15, qf_, ones, RA, oacc, sacc);
        if (++tt == nt) break;
        int nkb2 = ((tt + 1 < nt) ? tt + 1 : nt - 1) << 5;
        kv_load(kbh, vbh, nkb2, l15, g, RA);
        tile_compute(tt << 5, len, g, l15, qf_, ones, RB, oacc, sacc);
        if (++tt == nt) break;
    }

    // normalize (sacc in oacc row layout) and store O_flat (b, s, h*64+d) bf16
#pragma unroll
    for (int qf = 0; qf < 2; ++qf)
#pragma unroll
        for (int r = 0; r < 4; ++r) {
            float inv = 1.0f / sacc[qf][r];
            int s = qb + qf * 16 + g * 4 + r;
#pragma unroll
            for (int nf = 0; nf < 4; ++nf)
                of[((size_t)b * 2048 + s) * 512 + h * 64 + nf * 16 + l15] = f2bf(oacc[qf][nf][r] * inv);
        }
}

// ---------------- output projection GEMM (fp32 out) ----------------
__global__ __launch_bounds__(256) void oproj_kernel(const unsigned short* __restrict__ A,
        const unsigned short* __restrict__ W, const float* __restrict__ bo,
        float* __restrict__ out)
{
    __shared__ __align__(16) unsigned short As[128 * 64];
    __shared__ __align__(16) unsigned short Bs[128 * 64];
    int t = threadIdx.x, lane = t & 63, w = t >> 6;
    int g = lane >> 4, l15 = lane & 15;
    int wm = w >> 1, wn = w & 1;
    int mBase = blockIdx.x * 128, nBase = blockIdx.y * 128;

    int srow = t >> 3;
    int scol = (((t & 7) ^ (srow & 7))) * 8;
    const unsigned short* ag = A + (size_t)(mBase + srow) * 512 + scol;
    const unsigned short* bg = W + (size_t)(nBase + srow) * 512 + scol;
    char* al = (char*)As + t * 16;
    char* bl = (char*)Bs + t * 16;

    f32x4 acc[4][4] = {};

    for (int k0 = 0; k0 < 512; k0 += 64) {
        __syncthreads();
#pragma unroll
        for (int i = 0; i < 4; ++i) {
            gl16(ag + (size_t)i * 16384 + k0, al + i * 4096);
            gl16(bg + (size_t)i * 16384 + k0, bl + i * 4096);
        }
        __syncthreads();
#pragma unroll
        for (int ks = 0; ks < 2; ++ks) {
            s16x8 af[4], bf[4];
#pragma unroll
            for (int i = 0; i < 4; ++i) {
                int ar = wm * 64 + i * 16 + l15;
                af[i] = *(const s16x8*)((const char*)As + ar * 128 + ((ks * 64 + g * 16) ^ ((ar & 7) << 4)));
                int br = wn * 64 + i * 16 + l15;
                bf[i] = *(const s16x8*)((const char*)Bs + br * 128 + ((ks * 64 + g * 16) ^ ((br & 7) << 4)));
            }
            __builtin_amdgcn_s_setprio(1);
#pragma unroll
            for (int i = 0; i < 4; ++i)
#pragma unroll
                for (int j = 0; j < 4; ++j)
                    acc[i][j] = __builtin_amdgcn_mfma_f32_16x16x32_bf16(af[i], bf[j], acc[i][j], 0, 0, 0);
            __builtin_amdgcn_s_setprio(0);
        }
    }

#pragma unroll
    for (int i = 0; i < 4; ++i) {
        int row0 = mBase + wm * 64 + i * 16 + g * 4;
#pragma unroll
        for (int j = 0; j < 4; ++j) {
            int col = nBase + wn * 64 + j * 16 + l15;
            float bia = bo[col];
#pragma unroll
            for (int r = 0; r < 4; ++r)
                out[(size_t)(row0 + r) * 512 + col] = acc[i][j][r] + bia;
        }
    }
}

extern "C" void kernel_launch(void* const* d_in, const int* in_sizes, int n_in,
                              void* d_out, int out_size, void* d_ws, size_t ws_size,
                              hipStream_t stream) {
    (void)in_sizes; (void)n_in; (void)out_size; (void)ws_size;
    const float* x     = (const float*)d_in[0];
    const int*   lens  = (const int*)d_in[1];
    // d_in[2] = pos_embed (unused by reference)
    const float* gamma = (const float*)d_in[3];
    const float* beta  = (const float*)d_in[4];
    const float* Wq = (const float*)d_in[5];
    const float* bq = (const float*)d_in[6];
    const float* Wk = (const float*)d_in[7];
    const float* bk = (const float*)d_in[8];
    const float* Wv = (const float*)d_in[9];
    const float* bv = (const float*)d_in[10];
    const float* Wo = (const float*)d_in[11];
    const float* bo = (const float*)d_in[12];

    char* ws = (char*)d_ws;
    unsigned short* wbf = (unsigned short*)(ws);                         // 4 x 512x512 bf16
    unsigned short* xn  = (unsigned short*)(ws + (2ull  << 20));         // 8192x512 bf16
    unsigned short* qb_ = (unsigned short*)(ws + (10ull << 20));         // (b,h,s,dk)
    unsigned short* kb_ = (unsigned short*)(ws + (18ull << 20));         // (b,h,s,dk)
    unsigned short* vtb = (unsigned short*)(ws + (26ull << 20));         // (b,h,dk,s)
    unsigned short* ofb = (unsigned short*)(ws + (34ull << 20));         // 8192x512
    float* out = (float*)d_out;

    lnw_kernel<<<2304, 256, 0, stream>>>(x, gamma, beta, xn, Wq, Wk, Wv, Wo, wbf);
    qkv_kernel<<<dim3(64, 4, 3), 256, 0, stream>>>(xn, wbf, bq, bk, bv, qb_, kb_, vtb);
    attn_kernel<<<2048, 64, 0, stream>>>(qb_, kb_, vtb, lens, ofb);
    oproj_kernel<<<dim3(64, 4), 256, 0, stream>>>(ofb, wbf + 3 * 262144, bo, out);
}

// Round 6
// 113.895 us; speedup vs baseline: 1.4897x; 1.4897x over previous
//
#include <hip/hip_runtime.h>

typedef short s16x4 __attribute__((ext_vector_type(4)));
typedef short s16x8 __attribute__((ext_vector_type(8)));
typedef float f32x4 __attribute__((ext_vector_type(4)));
typedef unsigned int u32;

#define DEV static __device__ __forceinline__

// B=4, S=2048, D=512, H=8, DK=64, M = B*S = 8192

DEV unsigned short f2bf(float f) {
    unsigned u = __float_as_uint(f);
    u += 0x7FFFu + ((u >> 16) & 1u);   // RNE round to bf16
    return (unsigned short)(u >> 16);
}

DEV u32 cvtpk(float lo, float hi) {
    u32 r;
    asm("v_cvt_pk_bf16_f32 %0, %1, %2" : "=v"(r) : "v"(lo), "v"(hi));
    return r;
}
DEV void pl32swap(u32& a, u32& b) {
    asm("v_permlane32_swap_b32 %0, %1" : "+v"(a), "+v"(b));
}
DEV void pl16swap(u32& a, u32& b) {
    asm("v_permlane16_swap_b32 %0, %1" : "+v"(a), "+v"(b));
}
DEV void gl16(const void* g, void* l) {
    __builtin_amdgcn_global_load_lds((const __attribute__((address_space(1))) u32*)g,
                                     (__attribute__((address_space(3))) u32*)l, 16, 0, 0);
}

// ---------------- fused LayerNorm + weight convert ----------------
__global__ __launch_bounds__(256) void lnw_kernel(const float* __restrict__ x,
        const float* __restrict__ gamma, const float* __restrict__ beta,
        unsigned short* __restrict__ xn,
        const float* __restrict__ wq, const float* __restrict__ wk,
        const float* __restrict__ wv, const float* __restrict__ wo,
        unsigned short* __restrict__ wdst)
{
    if (blockIdx.x >= 2048) {
        int idx = blockIdx.x - 2048;
        int m = idx >> 6, sub = idx & 63;
        const float* src = (m == 0) ? wq : (m == 1) ? wk : (m == 2) ? wv : wo;
        unsigned short* d = wdst + (size_t)m * 262144;
        const f32x4* s4 = (const f32x4*)src;
        s16x4* d4 = (s16x4*)d;
#pragma unroll
        for (int i = 0; i < 4; ++i) {
            int e = sub * 1024 + i * 256 + threadIdx.x;
            f32x4 v = s4[e];
            s16x4 o;
            o[0] = f2bf(v[0]); o[1] = f2bf(v[1]); o[2] = f2bf(v[2]); o[3] = f2bf(v[3]);
            d4[e] = o;
        }
        return;
    }
    int t = threadIdx.x, w = t >> 6, lane = t & 63;
    int row = blockIdx.x * 4 + w;
    const float* xr = x + (size_t)row * 512 + lane * 8;
    f32x4 v0 = *(const f32x4*)xr;
    f32x4 v1 = *(const f32x4*)(xr + 4);
    float s = 0.f, s2 = 0.f;
#pragma unroll
    for (int i = 0; i < 4; ++i) { s += v0[i] + v1[i]; s2 += v0[i] * v0[i] + v1[i] * v1[i]; }
#pragma unroll
    for (int m = 1; m < 64; m <<= 1) { s += __shfl_xor(s, m); s2 += __shfl_xor(s2, m); }
    float mu = s * (1.f / 512.f);
    float var = s2 * (1.f / 512.f) - mu * mu;
    float rstd = rsqrtf(var + 1e-5f);
    f32x4 g0 = *(const f32x4*)(gamma + lane * 8);
    f32x4 g1 = *(const f32x4*)(gamma + lane * 8 + 4);
    f32x4 b0 = *(const f32x4*)(beta + lane * 8);
    f32x4 b1 = *(const f32x4*)(beta + lane * 8 + 4);
    s16x8 o;
#pragma unroll
    for (int i = 0; i < 4; ++i) {
        o[i]     = f2bf((v0[i] - mu) * rstd * g0[i] + b0[i]);
        o[i + 4] = f2bf((v1[i] - mu) * rstd * g1[i] + b1[i]);
    }
    *(s16x8*)(xn + (size_t)row * 512 + lane * 8) = o;
}

// ---------------- QKV projection GEMM ----------------
__global__ __launch_bounds__(256) void qkv_kernel(const unsigned short* __restrict__ xn,
        const unsigned short* __restrict__ wbase,
        const float* __restrict__ bq, const float* __restrict__ bk, const float* __restrict__ bv,
        unsigned short* __restrict__ qo, unsigned short* __restrict__ ko,
        unsigned short* __restrict__ vt)
{
    __shared__ __align__(16) unsigned short As[128 * 64];
    __shared__ __align__(16) unsigned short Bs[128 * 64];
    int z = blockIdx.z;
    const unsigned short* W = wbase + (size_t)z * 262144;
    const float* bias = (z == 0) ? bq : (z == 1) ? bk : bv;

    int t = threadIdx.x, lane = t & 63, w = t >> 6;
    int g = lane >> 4, l15 = lane & 15;
    int wm = w >> 1, wn = w & 1;
    int mBase = blockIdx.x * 128, nBase = blockIdx.y * 128;

    int srow = t >> 3;
    int scol = (((t & 7) ^ (srow & 7))) * 8;
    const unsigned short* ag = xn + (size_t)(mBase + srow) * 512 + scol;
    const unsigned short* bg = W + (size_t)(nBase + srow) * 512 + scol;
    char* al = (char*)As + t * 16;
    char* bl = (char*)Bs + t * 16;

    f32x4 acc[4][4] = {};

    for (int k0 = 0; k0 < 512; k0 += 64) {
        __syncthreads();
#pragma unroll
        for (int i = 0; i < 4; ++i) {
            gl16(ag + (size_t)i * 16384 + k0, al + i * 4096);
            gl16(bg + (size_t)i * 16384 + k0, bl + i * 4096);
        }
        __syncthreads();
#pragma unroll
        for (int ks = 0; ks < 2; ++ks) {
            s16x8 af[4], bf[4];
#pragma unroll
            for (int i = 0; i < 4; ++i) {
                int ar = wm * 64 + i * 16 + l15;
                af[i] = *(const s16x8*)((const char*)As + ar * 128 + ((ks * 64 + g * 16) ^ ((ar & 7) << 4)));
                int br = wn * 64 + i * 16 + l15;
                bf[i] = *(const s16x8*)((const char*)Bs + br * 128 + ((ks * 64 + g * 16) ^ ((br & 7) << 4)));
            }
            __builtin_amdgcn_s_setprio(1);
#pragma unroll
            for (int i = 0; i < 4; ++i)
#pragma unroll
                for (int j = 0; j < 4; ++j)
                    acc[i][j] = __builtin_amdgcn_mfma_f32_16x16x32_bf16(af[i], bf[j], acc[i][j], 0, 0, 0);
            __builtin_amdgcn_s_setprio(0);
        }
    }

#pragma unroll
    for (int i = 0; i < 4; ++i) {
        int row0 = mBase + wm * 64 + i * 16 + g * 4;
        int bb = row0 >> 11;
        int s0 = row0 & 2047;
#pragma unroll
        for (int j = 0; j < 4; ++j) {
            int col = nBase + wn * 64 + j * 16 + l15;
            float bia = bias[col];
            int h = col >> 6, dk = col & 63;
            if (z == 2) {
                s16x4 pk;
#pragma unroll
                for (int r = 0; r < 4; ++r) pk[r] = f2bf(acc[i][j][r] + bia);
                *(s16x4*)(vt + ((size_t)(bb * 8 + h) * 64 + dk) * 2048 + s0) = pk;
            } else {
                unsigned short* dst = (z == 0) ? qo : ko;
                float sc = (z == 0) ? 0.18033688011112042f : 1.0f;   // 0.125*log2(e)
#pragma unroll
                for (int r = 0; r < 4; ++r)
                    dst[((size_t)(bb * 8 + h) * 2048 + (s0 + r)) * 64 + dk] = f2bf((acc[i][j][r] + bia) * sc);
            }
        }
    }
}

// ---------------- flash attention ----------------
// grid 512, 128 thr = 2 waves x 64 q-rows (4 qf). KVBLK=64.
// 4 LDS buffers, 2-deep prefetch, ONE barrier per tile, counted vmcnt.
// bh = lin&31: each XCD serves bh in {h, h+8, h+16, h+24} -> all 4 b's
// (load balance) and 4 x 512KB K/V = 2MB fits per-XCD L2.
__global__ __launch_bounds__(128, 1) void attn_kernel(const unsigned short* __restrict__ q,
        const unsigned short* __restrict__ k, const unsigned short* __restrict__ vt,
        const int* __restrict__ lens, unsigned short* __restrict__ of)
{
    __shared__ __align__(16) unsigned short Ks[4][4096];    // [buf][64 k x 64 dk] 8KB
    __shared__ __align__(16) unsigned short Vts[4][4096];   // [buf][64 dk x 64 s] 8KB

    int t = threadIdx.x, lane = t & 63, w = t >> 6;
    int g = lane >> 4, l15 = lane & 15;
    int lin = blockIdx.x;
    int bh = lin & 31;
    int qi = lin >> 5;                 // 0..15
    int b = bh >> 3, h = bh & 7;
    int qb = qi * 128 + w * 64;
    int len = lens[b];
    int nt = (len + 63) >> 6;

    const unsigned short* kbh = k + (size_t)bh * 131072;
    const unsigned short* vbh = vt + (size_t)bh * 131072;

    // Q fragments (B-operand of S^T = K*Q): qf_[qf][ks]
    s16x8 qf_[4][2];
#pragma unroll
    for (int qf = 0; qf < 4; ++qf)
#pragma unroll
        for (int ks = 0; ks < 2; ++ks)
            qf_[qf][ks] = *(const s16x8*)(q + ((size_t)bh * 2048 + qb + qf * 16 + l15) * 64 + ks * 32 + g * 8);

    // staging: thread t covers 16B chunks; pre-swizzled source col
    int cr = t >> 3;                       // 0..15
    int cc = ((t & 7) ^ (cr & 7)) * 8;
    const unsigned short* kgp = kbh + cr * 64 + cc;
    const unsigned short* vgp = vbh + (size_t)cr * 2048 + cc;

    s16x8 ones;
#pragma unroll
    for (int i = 0; i < 8; ++i) ones[i] = (short)0x3F80;   // bf16 1.0

    f32x4 oacc[4][4] = {};   // [qf][nf]
    f32x4 sacc[4] = {};

#define STAGE(tile, buf) do { \
        const unsigned short* kp_ = kgp + (size_t)(tile) * 4096; \
        const unsigned short* vp_ = vgp + (tile) * 64; \
        char* kld_ = (char*)&Ks[buf][0] + t * 16; \
        char* vld_ = (char*)&Vts[buf][0] + t * 16; \
        _Pragma("unroll") \
        for (int i_ = 0; i_ < 4; ++i_) { \
            gl16(kp_ + i_ * 1024, kld_ + i_ * 2048); \
            gl16(vp_ + (size_t)i_ * 32768, vld_ + i_ * 2048); \
        } \
    } while (0)

    STAGE(0, 0);
    if (nt > 1) STAGE(1, 1);

    for (int tt = 0; tt < nt; ++tt) {
        int kb = tt << 6;
        if (tt + 2 < nt) {
            STAGE(tt + 2, (tt + 2) & 3);
            asm volatile("s_waitcnt vmcnt(16)" ::: "memory");   // tile tt landed; tt+1,tt+2 in flight
        } else if (tt + 1 < nt) {
            asm volatile("s_waitcnt vmcnt(8)" ::: "memory");
        } else {
            asm volatile("s_waitcnt vmcnt(0)" ::: "memory");
        }
        __builtin_amdgcn_s_barrier();          // all waves: tile tt visible, buf (tt+2)&3 free
        asm volatile("" ::: "memory");

        const char* Kb = (const char*)&Ks[tt & 3][0];
        const char* Vb = (const char*)&Vts[tt & 3][0];

        // QK^T -> S^T: sa[kf][qf]; S^T[k = kf*16+g*4+r][q = qf*16+l15]
        f32x4 sa[4][4] = {};
#pragma unroll
        for (int ks = 0; ks < 2; ++ks) {
            s16x8 ka[4];
#pragma unroll
            for (int kf = 0; kf < 4; ++kf) {
                int kr = kf * 16 + l15;
                ka[kf] = *(const s16x8*)(Kb + kr * 128 + ((ks * 64 + g * 16) ^ ((kr & 7) << 4)));
            }
            __builtin_amdgcn_s_setprio(1);
#pragma unroll
            for (int kf = 0; kf < 4; ++kf)
#pragma unroll
                for (int qf = 0; qf < 4; ++qf)
                    sa[kf][qf] = __builtin_amdgcn_mfma_f32_16x16x32_bf16(ka[kf], qf_[qf][ks], sa[kf][qf], 0, 0, 0);
            __builtin_amdgcn_s_setprio(0);
        }

        if (kb + 64 > len) {
            const float NEG = -__builtin_huge_valf();
#pragma unroll
            for (int kf = 0; kf < 4; ++kf)
#pragma unroll
                for (int r = 0; r < 4; ++r)
                    if (kb + kf * 16 + g * 4 + r >= len)
#pragma unroll
                        for (int qf = 0; qf < 4; ++qf) sa[kf][qf][r] = NEG;
        }

        // two k-halves: exp2 (fixed-max, scale folded into q) -> permlane P -> PV
#pragma unroll
        for (int half = 0; half < 2; ++half) {
            s16x8 vbf[4];
#pragma unroll
            for (int nf = 0; nf < 4; ++nf) {
                int dr = nf * 16 + l15;
                vbf[nf] = *(const s16x8*)(Vb + dr * 128 + ((half * 64 + g * 16) ^ ((dr & 7) << 4)));
            }
            u32 pkd[2][4][2];
#pragma unroll
            for (int qf = 0; qf < 4; ++qf)
#pragma unroll
                for (int k2 = 0; k2 < 2; ++k2) {
                    int kf = half * 2 + k2;
#pragma unroll
                    for (int r = 0; r < 4; ++r)
                        sa[kf][qf][r] = __builtin_amdgcn_exp2f(sa[kf][qf][r]);
                    pkd[k2][qf][0] = cvtpk(sa[kf][qf][0], sa[kf][qf][1]);
                    pkd[k2][qf][1] = cvtpk(sa[kf][qf][2], sa[kf][qf][3]);
                }
            __builtin_amdgcn_s_setprio(1);
#pragma unroll
            for (int qf = 0; qf < 4; ++qf) {
                u32 a0 = pkd[0][qf][0], b0 = pkd[1][qf][0];
                u32 a1 = pkd[0][qf][1], b1 = pkd[1][qf][1];
                pl32swap(a0, b0); pl16swap(a0, b0);
                pl32swap(a1, b1); pl16swap(a1, b1);
                union { u32 d[4]; s16x8 v; } pf;
                pf.d[0] = a0; pf.d[1] = a1; pf.d[2] = b0; pf.d[3] = b1;
                sacc[qf] = __builtin_amdgcn_mfma_f32_16x16x32_bf16(pf.v, ones, sacc[qf], 0, 0, 0);
#pragma unroll
                for (int nf = 0; nf < 4; ++nf)
                    oacc[qf][nf] = __builtin_amdgcn_mfma_f32_16x16x32_bf16(pf.v, vbf[nf], oacc[qf][nf], 0, 0, 0);
            }
            __builtin_amdgcn_s_setprio(0);
        }
        asm volatile("" ::: "memory");
    }
#undef STAGE

    // normalize (sacc in oacc row layout) and store O_flat (b, s, h*64+d) bf16
#pragma unroll
    for (int qf = 0; qf < 4; ++qf)
#pragma unroll
        for (int r = 0; r < 4; ++r) {
            float inv = 1.0f / sacc[qf][r];
            int s = qb + qf * 16 + g * 4 + r;
#pragma unroll
            for (int nf = 0; nf < 4; ++nf)
                of[((size_t)b * 2048 + s) * 512 + h * 64 + nf * 16 + l15] = f2bf(oacc[qf][nf][r] * inv);
        }
}

// ---------------- output projection GEMM (fp32 out) ----------------
__global__ __launch_bounds__(256) void oproj_kernel(const unsigned short* __restrict__ A,
        const unsigned short* __restrict__ W, const float* __restrict__ bo,
        float* __restrict__ out)
{
    __shared__ __align__(16) unsigned short As[128 * 64];
    __shared__ __align__(16) unsigned short Bs[128 * 64];
    int t = threadIdx.x, lane = t & 63, w = t >> 6;
    int g = lane >> 4, l15 = lane & 15;
    int wm = w >> 1, wn = w & 1;
    int mBase = blockIdx.x * 128, nBase = blockIdx.y * 128;

    int srow = t >> 3;
    int scol = (((t & 7) ^ (srow & 7))) * 8;
    const unsigned short* ag = A + (size_t)(mBase + srow) * 512 + scol;
    const unsigned short* bg = W + (size_t)(nBase + srow) * 512 + scol;
    char* al = (char*)As + t * 16;
    char* bl = (char*)Bs + t * 16;

    f32x4 acc[4][4] = {};

    for (int k0 = 0; k0 < 512; k0 += 64) {
        __syncthreads();
#pragma unroll
        for (int i = 0; i < 4; ++i) {
            gl16(ag + (size_t)i * 16384 + k0, al + i * 4096);
            gl16(bg + (size_t)i * 16384 + k0, bl + i * 4096);
        }
        __syncthreads();
#pragma unroll
        for (int ks = 0; ks < 2; ++ks) {
            s16x8 af[4], bf[4];
#pragma unroll
            for (int i = 0; i < 4; ++i) {
                int ar = wm * 64 + i * 16 + l15;
                af[i] = *(const s16x8*)((const char*)As + ar * 128 + ((ks * 64 + g * 16) ^ ((ar & 7) << 4)));
                int br = wn * 64 + i * 16 + l15;
                bf[i] = *(const s16x8*)((const char*)Bs + br * 128 + ((ks * 64 + g * 16) ^ ((br & 7) << 4)));
            }
            __builtin_amdgcn_s_setprio(1);
#pragma unroll
            for (int i = 0; i < 4; ++i)
#pragma unroll
                for (int j = 0; j < 4; ++j)
                    acc[i][j] = __builtin_amdgcn_mfma_f32_16x16x32_bf16(af[i], bf[j], acc[i][j], 0, 0, 0);
            __builtin_amdgcn_s_setprio(0);
        }
    }

#pragma unroll
    for (int i = 0; i < 4; ++i) {
        int row0 = mBase + wm * 64 + i * 16 + g * 4;
#pragma unroll
        for (int j = 0; j < 4; ++j) {
            int col = nBase + wn * 64 + j * 16 + l15;
            float bia = bo[col];
#pragma unroll
            for (int r = 0; r < 4; ++r)
                out[(size_t)(row0 + r) * 512 + col] = acc[i][j][r] + bia;
        }
    }
}

extern "C" void kernel_launch(void* const* d_in, const int* in_sizes, int n_in,
                              void* d_out, int out_size, void* d_ws, size_t ws_size,
                              hipStream_t stream) {
    (void)in_sizes; (void)n_in; (void)out_size; (void)ws_size;
    const float* x     = (const float*)d_in[0];
    const int*   lens  = (const int*)d_in[1];
    // d_in[2] = pos_embed (unused by reference)
    const float* gamma = (const float*)d_in[3];
    const float* beta  = (const float*)d_in[4];
    const float* Wq = (const float*)d_in[5];
    const float* bq = (const float*)d_in[6];
    const float* Wk = (const float*)d_in[7];
    const float* bk = (const float*)d_in[8];
    const float* Wv = (const float*)d_in[9];
    const float* bv = (const float*)d_in[10];
    const float* Wo = (const float*)d_in[11];
    const float* bo = (const float*)d_in[12];

    char* ws = (char*)d_ws;
    unsigned short* wbf = (unsigned short*)(ws);                         // 4 x 512x512 bf16
    unsigned short* xn  = (unsigned short*)(ws + (2ull  << 20));         // 8192x512 bf16
    unsigned short* qb_ = (unsigned short*)(ws + (10ull << 20));         // (b,h,s,dk)
    unsigned short* kb_ = (unsigned short*)(ws + (18ull << 20));         // (b,h,s,dk)
    unsigned short* vtb = (unsigned short*)(ws + (26ull << 20));         // (b,h,dk,s)
    unsigned short* ofb = (unsigned short*)(ws + (34ull << 20));         // 8192x512
    float* out = (float*)d_out;

    lnw_kernel<<<2304, 256, 0, stream>>>(x, gamma, beta, xn, Wq, Wk, Wv, Wo, wbf);
    qkv_kernel<<<dim3(64, 4, 3), 256, 0, stream>>>(xn, wbf, bq, bk, bv, qb_, kb_, vtb);
    attn_kernel<<<512, 128, 0, stream>>>(qb_, kb_, vtb, lens, ofb);
    oproj_kernel<<<dim3(64, 4), 256, 0, stream>>>(ofb, wbf + 3 * 262144, bo, out);
}

// Round 7
// 97.989 us; speedup vs baseline: 1.7315x; 1.1623x over previous
//
#include <hip/hip_runtime.h>

typedef short s16x4 __attribute__((ext_vector_type(4)));
typedef short s16x8 __attribute__((ext_vector_type(8)));
typedef float f32x4 __attribute__((ext_vector_type(4)));
typedef unsigned int u32;

#define DEV static __device__ __forceinline__

// B=4, S=2048, D=512, H=8, DK=64, M = B*S = 8192

DEV unsigned short f2bf(float f) {
    unsigned u = __float_as_uint(f);
    u += 0x7FFFu + ((u >> 16) & 1u);   // RNE round to bf16
    return (unsigned short)(u >> 16);
}

DEV u32 cvtpk(float lo, float hi) {
    u32 r;
    asm("v_cvt_pk_bf16_f32 %0, %1, %2" : "=v"(r) : "v"(lo), "v"(hi));
    return r;
}
DEV void pl32swap(u32& a, u32& b) {
    asm("v_permlane32_swap_b32 %0, %1" : "+v"(a), "+v"(b));
}
DEV void pl16swap(u32& a, u32& b) {
    asm("v_permlane16_swap_b32 %0, %1" : "+v"(a), "+v"(b));
}
DEV void gl16(const void* g, void* l) {
    __builtin_amdgcn_global_load_lds((const __attribute__((address_space(1))) u32*)g,
                                     (__attribute__((address_space(3))) u32*)l, 16, 0, 0);
}

// ---------------- fused LayerNorm + weight convert ----------------
__global__ __launch_bounds__(256) void lnw_kernel(const float* __restrict__ x,
        const float* __restrict__ gamma, const float* __restrict__ beta,
        unsigned short* __restrict__ xn,
        const float* __restrict__ wq, const float* __restrict__ wk,
        const float* __restrict__ wv, const float* __restrict__ wo,
        unsigned short* __restrict__ wdst)
{
    if (blockIdx.x >= 2048) {
        int idx = blockIdx.x - 2048;
        int m = idx >> 6, sub = idx & 63;
        const float* src = (m == 0) ? wq : (m == 1) ? wk : (m == 2) ? wv : wo;
        unsigned short* d = wdst + (size_t)m * 262144;
        const f32x4* s4 = (const f32x4*)src;
        s16x4* d4 = (s16x4*)d;
#pragma unroll
        for (int i = 0; i < 4; ++i) {
            int e = sub * 1024 + i * 256 + threadIdx.x;
            f32x4 v = s4[e];
            s16x4 o;
            o[0] = f2bf(v[0]); o[1] = f2bf(v[1]); o[2] = f2bf(v[2]); o[3] = f2bf(v[3]);
            d4[e] = o;
        }
        return;
    }
    int t = threadIdx.x, w = t >> 6, lane = t & 63;
    int row = blockIdx.x * 4 + w;
    const float* xr = x + (size_t)row * 512 + lane * 8;
    f32x4 v0 = *(const f32x4*)xr;
    f32x4 v1 = *(const f32x4*)(xr + 4);
    float s = 0.f, s2 = 0.f;
#pragma unroll
    for (int i = 0; i < 4; ++i) { s += v0[i] + v1[i]; s2 += v0[i] * v0[i] + v1[i] * v1[i]; }
#pragma unroll
    for (int m = 1; m < 64; m <<= 1) { s += __shfl_xor(s, m); s2 += __shfl_xor(s2, m); }
    float mu = s * (1.f / 512.f);
    float var = s2 * (1.f / 512.f) - mu * mu;
    float rstd = rsqrtf(var + 1e-5f);
    f32x4 g0 = *(const f32x4*)(gamma + lane * 8);
    f32x4 g1 = *(const f32x4*)(gamma + lane * 8 + 4);
    f32x4 b0 = *(const f32x4*)(beta + lane * 8);
    f32x4 b1 = *(const f32x4*)(beta + lane * 8 + 4);
    s16x8 o;
#pragma unroll
    for (int i = 0; i < 4; ++i) {
        o[i]     = f2bf((v0[i] - mu) * rstd * g0[i] + b0[i]);
        o[i + 4] = f2bf((v1[i] - mu) * rstd * g1[i] + b1[i]);
    }
    *(s16x8*)(xn + (size_t)row * 512 + lane * 8) = o;
}

// ---------------- QKV projection GEMM ----------------
__global__ __launch_bounds__(256) void qkv_kernel(const unsigned short* __restrict__ xn,
        const unsigned short* __restrict__ wbase,
        const float* __restrict__ bq, const float* __restrict__ bk, const float* __restrict__ bv,
        unsigned short* __restrict__ qo, unsigned short* __restrict__ ko,
        unsigned short* __restrict__ vt)
{
    __shared__ __align__(16) unsigned short As[128 * 64];
    __shared__ __align__(16) unsigned short Bs[128 * 64];
    int z = blockIdx.z;
    const unsigned short* W = wbase + (size_t)z * 262144;
    const float* bias = (z == 0) ? bq : (z == 1) ? bk : bv;

    int t = threadIdx.x, lane = t & 63, w = t >> 6;
    int g = lane >> 4, l15 = lane & 15;
    int wm = w >> 1, wn = w & 1;
    int mBase = blockIdx.x * 128, nBase = blockIdx.y * 128;

    int srow = t >> 3;
    int scol = (((t & 7) ^ (srow & 7))) * 8;
    const unsigned short* ag = xn + (size_t)(mBase + srow) * 512 + scol;
    const unsigned short* bg = W + (size_t)(nBase + srow) * 512 + scol;
    char* al = (char*)As + t * 16;
    char* bl = (char*)Bs + t * 16;

    f32x4 acc[4][4] = {};

    for (int k0 = 0; k0 < 512; k0 += 64) {
        __syncthreads();
#pragma unroll
        for (int i = 0; i < 4; ++i) {
            gl16(ag + (size_t)i * 16384 + k0, al + i * 4096);
            gl16(bg + (size_t)i * 16384 + k0, bl + i * 4096);
        }
        __syncthreads();
#pragma unroll
        for (int ks = 0; ks < 2; ++ks) {
            s16x8 af[4], bf[4];
#pragma unroll
            for (int i = 0; i < 4; ++i) {
                int ar = wm * 64 + i * 16 + l15;
                af[i] = *(const s16x8*)((const char*)As + ar * 128 + ((ks * 64 + g * 16) ^ ((ar & 7) << 4)));
                int br = wn * 64 + i * 16 + l15;
                bf[i] = *(const s16x8*)((const char*)Bs + br * 128 + ((ks * 64 + g * 16) ^ ((br & 7) << 4)));
            }
            __builtin_amdgcn_s_setprio(1);
#pragma unroll
            for (int i = 0; i < 4; ++i)
#pragma unroll
                for (int j = 0; j < 4; ++j)
                    acc[i][j] = __builtin_amdgcn_mfma_f32_16x16x32_bf16(af[i], bf[j], acc[i][j], 0, 0, 0);
            __builtin_amdgcn_s_setprio(0);
        }
    }

#pragma unroll
    for (int i = 0; i < 4; ++i) {
        int row0 = mBase + wm * 64 + i * 16 + g * 4;
        int bb = row0 >> 11;
        int s0 = row0 & 2047;
#pragma unroll
        for (int j = 0; j < 4; ++j) {
            int col = nBase + wn * 64 + j * 16 + l15;
            float bia = bias[col];
            int h = col >> 6, dk = col & 63;
            if (z == 2) {
                s16x4 pk;
#pragma unroll
                for (int r = 0; r < 4; ++r) pk[r] = f2bf(acc[i][j][r] + bia);
                *(s16x4*)(vt + ((size_t)(bb * 8 + h) * 64 + dk) * 2048 + s0) = pk;
            } else {
                unsigned short* dst = (z == 0) ? qo : ko;
                float sc = (z == 0) ? 0.18033688011112042f : 1.0f;   // 0.125*log2(e)
#pragma unroll
                for (int r = 0; r < 4; ++r)
                    dst[((size_t)(bb * 8 + h) * 2048 + (s0 + r)) * 64 + dk] = f2bf((acc[i][j][r] + bia) * sc);
            }
        }
    }
}

// ---------------- flash attention, KV-split-2, fp32 linear partials ----------------
// grid 1024, 256 thr = 4 waves x 32 q-rows (128 q/block). KVBLK=64, 2-buf LDS (32KB),
// counted vmcnt(4) + 2 barriers/tile (r4-proven scheme). 4 blocks/CU -> 4 waves/SIMD.
// lin&31 = bh (all 4 batches per XCD, 2MB K/V L2-resident); split = (lin>>5)&1.
__global__ __launch_bounds__(256, 4) void attn_kernel(const unsigned short* __restrict__ q,
        const unsigned short* __restrict__ k, const unsigned short* __restrict__ vt,
        const int* __restrict__ lens, float* __restrict__ o_part, float* __restrict__ l_part)
{
    __shared__ __align__(16) unsigned short Ks[2][4096];    // [buf][64k x 64dk] 8KB
    __shared__ __align__(16) unsigned short Vts[2][4096];   // [buf][64dk x 64s] 8KB

    int t = threadIdx.x, lane = t & 63, w = t >> 6;
    int g = lane >> 4, l15 = lane & 15;
    int lin = blockIdx.x;
    int bh = lin & 31;
    int rest = lin >> 5;               // 0..31
    int split = rest & 1;
    int qt = rest >> 1;                // 0..15
    int b = bh >> 3, h = bh & 7;
    int qb = qt * 128 + w * 32;
    int len = lens[b];
    int ntf = (len + 63) >> 6;
    int nt0 = (ntf + 1) >> 1;
    int tbeg = split ? nt0 : 0;
    int ntX = (split ? ntf : nt0) - tbeg;

    const unsigned short* kbh = k + (size_t)bh * 131072;
    const unsigned short* vbh = vt + (size_t)bh * 131072;

    // Q fragments (B-operand of S^T = K*Q)
    s16x8 qf_[2][2];
#pragma unroll
    for (int qf = 0; qf < 2; ++qf)
#pragma unroll
        for (int ks = 0; ks < 2; ++ks)
            qf_[qf][ks] = *(const s16x8*)(q + ((size_t)bh * 2048 + qb + qf * 16 + l15) * 64 + ks * 32 + g * 8);

    // staging: 256 thr cover 512 chunks of 16B per 8KB tile (2 gl16 K + 2 gl16 V each)
    int cr = t >> 3;                       // 0..31
    int cc = ((t & 7) ^ (cr & 7)) * 8;     // pre-swizzled source col
    const unsigned short* kgp = kbh + cr * 64 + cc;
    const unsigned short* vgp = vbh + (size_t)cr * 2048 + cc;

    s16x8 ones;
#pragma unroll
    for (int i = 0; i < 8; ++i) ones[i] = (short)0x3F80;   // bf16 1.0

    f32x4 oacc[2][4] = {};   // [qf][nf]
    f32x4 sacc[2] = {};

#define STAGE(tile, buf) do { \
        const unsigned short* kp_ = kgp + (size_t)(tile) * 4096; \
        const unsigned short* vp_ = vgp + (tile) * 64; \
        char* kld_ = (char*)&Ks[buf][0] + t * 16; \
        char* vld_ = (char*)&Vts[buf][0] + t * 16; \
        gl16(kp_, kld_);          gl16(kp_ + 2048, kld_ + 4096); \
        gl16(vp_, vld_);          gl16(vp_ + 65536, vld_ + 4096); \
    } while (0)

    STAGE(tbeg, 0);

    for (int li = 0; li < ntX; ++li) {
        int tt = tbeg + li;
        int kb = tt << 6;
        asm volatile("" ::: "memory");
        __builtin_amdgcn_s_barrier();              // compute of li-1 done -> buf (li+1)&1 free
        if (li + 1 < ntX) {
            STAGE(tt + 1, (li + 1) & 1);
            asm volatile("s_waitcnt vmcnt(4)" ::: "memory");   // tile li landed; li+1 in flight
        } else {
            asm volatile("s_waitcnt vmcnt(0)" ::: "memory");
        }
        __builtin_amdgcn_s_barrier();              // tile li visible to all 4 waves
        asm volatile("" ::: "memory");

        const char* Kb = (const char*)&Ks[li & 1][0];
        const char* Vb = (const char*)&Vts[li & 1][0];

        // QK^T -> S^T: sa[kf][qf]; S^T[k = kf*16+g*4+r][q = qf*16+l15]
        f32x4 sa[4][2] = {};
#pragma unroll
        for (int ks = 0; ks < 2; ++ks) {
            s16x8 ka[4];
#pragma unroll
            for (int kf = 0; kf < 4; ++kf) {
                int kr = kf * 16 + l15;
                ka[kf] = *(const s16x8*)(Kb + kr * 128 + ((ks * 64 + g * 16) ^ ((kr & 7) << 4)));
            }
            __builtin_amdgcn_s_setprio(1);
#pragma unroll
            for (int kf = 0; kf < 4; ++kf)
#pragma unroll
                for (int qf = 0; qf < 2; ++qf)
                    sa[kf][qf] = __builtin_amdgcn_mfma_f32_16x16x32_bf16(ka[kf], qf_[qf][ks], sa[kf][qf], 0, 0, 0);
            __builtin_amdgcn_s_setprio(0);
        }

        if (kb + 64 > len) {
            const float NEG = -__builtin_huge_valf();
#pragma unroll
            for (int kf = 0; kf < 4; ++kf)
#pragma unroll
                for (int r = 0; r < 4; ++r)
                    if (kb + kf * 16 + g * 4 + r >= len) { sa[kf][0][r] = NEG; sa[kf][1][r] = NEG; }
        }

        // two k-halves: exp2 (fixed-max, scale folded into q) -> permlane P -> PV
#pragma unroll
        for (int half = 0; half < 2; ++half) {
            s16x8 vbf[4];
#pragma unroll
            for (int nf = 0; nf < 4; ++nf) {
                int dr = nf * 16 + l15;
                vbf[nf] = *(const s16x8*)(Vb + dr * 128 + ((half * 64 + g * 16) ^ ((dr & 7) << 4)));
            }
            u32 pkd[2][2][2];
#pragma unroll
            for (int qf = 0; qf < 2; ++qf)
#pragma unroll
                for (int k2 = 0; k2 < 2; ++k2) {
                    int kf = half * 2 + k2;
#pragma unroll
                    for (int r = 0; r < 4; ++r)
                        sa[kf][qf][r] = __builtin_amdgcn_exp2f(sa[kf][qf][r]);
                    pkd[k2][qf][0] = cvtpk(sa[kf][qf][0], sa[kf][qf][1]);
                    pkd[k2][qf][1] = cvtpk(sa[kf][qf][2], sa[kf][qf][3]);
                }
            __builtin_amdgcn_s_setprio(1);
#pragma unroll
            for (int qf = 0; qf < 2; ++qf) {
                u32 a0 = pkd[0][qf][0], b0 = pkd[1][qf][0];
                u32 a1 = pkd[0][qf][1], b1 = pkd[1][qf][1];
                pl32swap(a0, b0); pl16swap(a0, b0);
                pl32swap(a1, b1); pl16swap(a1, b1);
                union { u32 d[4]; s16x8 v; } pf;
                pf.d[0] = a0; pf.d[1] = a1; pf.d[2] = b0; pf.d[3] = b1;
                sacc[qf] = __builtin_amdgcn_mfma_f32_16x16x32_bf16(pf.v, ones, sacc[qf], 0, 0, 0);
#pragma unroll
                for (int nf = 0; nf < 4; ++nf)
                    oacc[qf][nf] = __builtin_amdgcn_mfma_f32_16x16x32_bf16(pf.v, vbf[nf], oacc[qf][nf], 0, 0, 0);
            }
            __builtin_amdgcn_s_setprio(0);
        }
        asm volatile("" ::: "memory");
    }
#undef STAGE

    // write fp32 partials (unnormalized O, and l in oacc row layout)
    float* op = o_part + (size_t)split * (8192 * 512);
#pragma unroll
    for (int qf = 0; qf < 2; ++qf)
#pragma unroll
        for (int r = 0; r < 4; ++r) {
            int s = qb + qf * 16 + g * 4 + r;
#pragma unroll
            for (int nf = 0; nf < 4; ++nf)
                op[(size_t)(b * 2048 + s) * 512 + h * 64 + nf * 16 + l15] = oacc[qf][nf][r];
        }
    float* lp = l_part + split * 65536 + bh * 2048;
    if (l15 == 0) {
#pragma unroll
        for (int qf = 0; qf < 2; ++qf)
#pragma unroll
            for (int r = 0; r < 4; ++r)
                lp[qb + qf * 16 + g * 4 + r] = sacc[qf][r];
    }
}

// ---------------- combine: (O0+O1)/(l0+l1) -> bf16 ----------------
__global__ __launch_bounds__(256) void comb_kernel(const float* __restrict__ o_part,
        const float* __restrict__ l_part, unsigned short* __restrict__ A)
{
    int t = threadIdx.x;
    int row = blockIdx.x * 2 + (t >> 7);
    int cq = t & 127;                  // f32x4 column index (col = cq*4)
    int b = row >> 11, s = row & 2047, h = cq >> 4;
    const f32x4* o4 = (const f32x4*)o_part;
    f32x4 a = o4[(size_t)row * 128 + cq];
    f32x4 c = o4[(size_t)(8192 + row) * 128 + cq];
    float l = l_part[(b * 8 + h) * 2048 + s] + l_part[65536 + (b * 8 + h) * 2048 + s];
    float inv = 1.f / l;
    s16x4 o;
#pragma unroll
    for (int i = 0; i < 4; ++i) o[i] = f2bf((a[i] + c[i]) * inv);
    *(s16x4*)(A + (size_t)row * 512 + cq * 4) = o;
}

// ---------------- output projection GEMM (fp32 out) ----------------
__global__ __launch_bounds__(256) void oproj_kernel(const unsigned short* __restrict__ A,
        const unsigned short* __restrict__ W, const float* __restrict__ bo,
        float* __restrict__ out)
{
    __shared__ __align__(16) unsigned short As[128 * 64];
    __shared__ __align__(16) unsigned short Bs[128 * 64];
    int t = threadIdx.x, lane = t & 63, w = t >> 6;
    int g = lane >> 4, l15 = lane & 15;
    int wm = w >> 1, wn = w & 1;
    int mBase = blockIdx.x * 128, nBase = blockIdx.y * 128;

    int srow = t >> 3;
    int scol = (((t & 7) ^ (srow & 7))) * 8;
    const unsigned short* ag = A + (size_t)(mBase + srow) * 512 + scol;
    const unsigned short* bg = W + (size_t)(nBase + srow) * 512 + scol;
    char* al = (char*)As + t * 16;
    char* bl = (char*)Bs + t * 16;

    f32x4 acc[4][4] = {};

    for (int k0 = 0; k0 < 512; k0 += 64) {
        __syncthreads();
#pragma unroll
        for (int i = 0; i < 4; ++i) {
            gl16(ag + (size_t)i * 16384 + k0, al + i * 4096);
            gl16(bg + (size_t)i * 16384 + k0, bl + i * 4096);
        }
        __syncthreads();
#pragma unroll
        for (int ks = 0; ks < 2; ++ks) {
            s16x8 af[4], bf[4];
#pragma unroll
            for (int i = 0; i < 4; ++i) {
                int ar = wm * 64 + i * 16 + l15;
                af[i] = *(const s16x8*)((const char*)As + ar * 128 + ((ks * 64 + g * 16) ^ ((ar & 7) << 4)));
                int br = wn * 64 + i * 16 + l15;
                bf[i] = *(const s16x8*)((const char*)Bs + br * 128 + ((ks * 64 + g * 16) ^ ((br & 7) << 4)));
            }
            __builtin_amdgcn_s_setprio(1);
#pragma unroll
            for (int i = 0; i < 4; ++i)
#pragma unroll
                for (int j = 0; j < 4; ++j)
                    acc[i][j] = __builtin_amdgcn_mfma_f32_16x16x32_bf16(af[i], bf[j], acc[i][j], 0, 0, 0);
            __builtin_amdgcn_s_setprio(0);
        }
    }

#pragma unroll
    for (int i = 0; i < 4; ++i) {
        int row0 = mBase + wm * 64 + i * 16 + g * 4;
#pragma unroll
        for (int j = 0; j < 4; ++j) {
            int col = nBase + wn * 64 + j * 16 + l15;
            float bia = bo[col];
#pragma unroll
            for (int r = 0; r < 4; ++r)
                out[(size_t)(row0 + r) * 512 + col] = acc[i][j][r] + bia;
        }
    }
}

extern "C" void kernel_launch(void* const* d_in, const int* in_sizes, int n_in,
                              void* d_out, int out_size, void* d_ws, size_t ws_size,
                              hipStream_t stream) {
    (void)in_sizes; (void)n_in; (void)out_size; (void)ws_size;
    const float* x     = (const float*)d_in[0];
    const int*   lens  = (const int*)d_in[1];
    // d_in[2] = pos_embed (unused by reference)
    const float* gamma = (const float*)d_in[3];
    const float* beta  = (const float*)d_in[4];
    const float* Wq = (const float*)d_in[5];
    const float* bq = (const float*)d_in[6];
    const float* Wk = (const float*)d_in[7];
    const float* bk = (const float*)d_in[8];
    const float* Wv = (const float*)d_in[9];
    const float* bv = (const float*)d_in[10];
    const float* Wo = (const float*)d_in[11];
    const float* bo = (const float*)d_in[12];

    char* ws = (char*)d_ws;
    unsigned short* wbf = (unsigned short*)(ws);                  // 0..2MB: 4x512x512 bf16
    unsigned short* xn  = (unsigned short*)(ws + (2ull  << 20));  // 2..10MB: LN out / attn-combined (oproj A)
    unsigned short* qb_ = (unsigned short*)(ws + (10ull << 20));  // (b,h,s,dk)
    unsigned short* kb_ = (unsigned short*)(ws + (18ull << 20));  // (b,h,s,dk)
    unsigned short* vtb = (unsigned short*)(ws + (26ull << 20));  // (b,h,dk,s)
    float* o_part = (float*)(ws + (34ull << 20));                 // 34..66MB: [2][8192][512] f32
    float* l_part = (float*)(ws + (66ull << 20));                 // 66..66.5MB: [2][32][2048] f32
    float* out = (float*)d_out;

    lnw_kernel<<<2304, 256, 0, stream>>>(x, gamma, beta, xn, Wq, Wk, Wv, Wo, wbf);
    qkv_kernel<<<dim3(64, 4, 3), 256, 0, stream>>>(xn, wbf, bq, bk, bv, qb_, kb_, vtb);
    attn_kernel<<<1024, 256, 0, stream>>>(qb_, kb_, vtb, lens, o_part, l_part);
    comb_kernel<<<4096, 256, 0, stream>>>(o_part, l_part, xn);
    oproj_kernel<<<dim3(64, 4), 256, 0, stream>>>(xn, wbf + 3 * 262144, bo, out);
}

// Round 8
// 91.985 us; speedup vs baseline: 1.8446x; 1.0653x over previous
//
#include <hip/hip_runtime.h>

typedef short s16x4 __attribute__((ext_vector_type(4)));
typedef short s16x8 __attribute__((ext_vector_type(8)));
typedef float f32x4 __attribute__((ext_vector_type(4)));
typedef unsigned int u32;

#define DEV static __device__ __forceinline__

// B=4, S=2048, D=512, H=8, DK=64, M = B*S = 8192

DEV unsigned short f2bf(float f) {
    unsigned u = __float_as_uint(f);
    u += 0x7FFFu + ((u >> 16) & 1u);   // RNE round to bf16
    return (unsigned short)(u >> 16);
}

DEV u32 cvtpk(float lo, float hi) {
    u32 r;
    asm("v_cvt_pk_bf16_f32 %0, %1, %2" : "=v"(r) : "v"(lo), "v"(hi));
    return r;
}
DEV void pl32swap(u32& a, u32& b) {
    asm("v_permlane32_swap_b32 %0, %1" : "+v"(a), "+v"(b));
}
DEV void pl16swap(u32& a, u32& b) {
    asm("v_permlane16_swap_b32 %0, %1" : "+v"(a), "+v"(b));
}
DEV void gl16(const void* g, void* l) {
    __builtin_amdgcn_global_load_lds((const __attribute__((address_space(1))) u32*)g,
                                     (__attribute__((address_space(3))) u32*)l, 16, 0, 0);
}

// ---------------- fused LayerNorm + weight convert ----------------
__global__ __launch_bounds__(256) void lnw_kernel(const float* __restrict__ x,
        const float* __restrict__ gamma, const float* __restrict__ beta,
        unsigned short* __restrict__ xn,
        const float* __restrict__ wq, const float* __restrict__ wk,
        const float* __restrict__ wv, const float* __restrict__ wo,
        unsigned short* __restrict__ wdst)
{
    if (blockIdx.x >= 2048) {
        int idx = blockIdx.x - 2048;
        int m = idx >> 6, sub = idx & 63;
        const float* src = (m == 0) ? wq : (m == 1) ? wk : (m == 2) ? wv : wo;
        unsigned short* d = wdst + (size_t)m * 262144;
        const f32x4* s4 = (const f32x4*)src;
        s16x4* d4 = (s16x4*)d;
#pragma unroll
        for (int i = 0; i < 4; ++i) {
            int e = sub * 1024 + i * 256 + threadIdx.x;
            f32x4 v = s4[e];
            s16x4 o;
            o[0] = f2bf(v[0]); o[1] = f2bf(v[1]); o[2] = f2bf(v[2]); o[3] = f2bf(v[3]);
            d4[e] = o;
        }
        return;
    }
    int t = threadIdx.x, w = t >> 6, lane = t & 63;
    int row = blockIdx.x * 4 + w;
    const float* xr = x + (size_t)row * 512 + lane * 8;
    f32x4 v0 = *(const f32x4*)xr;
    f32x4 v1 = *(const f32x4*)(xr + 4);
    float s = 0.f, s2 = 0.f;
#pragma unroll
    for (int i = 0; i < 4; ++i) { s += v0[i] + v1[i]; s2 += v0[i] * v0[i] + v1[i] * v1[i]; }
#pragma unroll
    for (int m = 1; m < 64; m <<= 1) { s += __shfl_xor(s, m); s2 += __shfl_xor(s2, m); }
    float mu = s * (1.f / 512.f);
    float var = s2 * (1.f / 512.f) - mu * mu;
    float rstd = rsqrtf(var + 1e-5f);
    f32x4 g0 = *(const f32x4*)(gamma + lane * 8);
    f32x4 g1 = *(const f32x4*)(gamma + lane * 8 + 4);
    f32x4 b0 = *(const f32x4*)(beta + lane * 8);
    f32x4 b1 = *(const f32x4*)(beta + lane * 8 + 4);
    s16x8 o;
#pragma unroll
    for (int i = 0; i < 4; ++i) {
        o[i]     = f2bf((v0[i] - mu) * rstd * g0[i] + b0[i]);
        o[i + 4] = f2bf((v1[i] - mu) * rstd * g1[i] + b1[i]);
    }
    *(s16x8*)(xn + (size_t)row * 512 + lane * 8) = o;
}

// ---------------- pipelined 128x128 GEMM core (BK=32, 3-buf, depth-2 prefetch) ----------------
// LDS tile [128 rows][32 k] bf16, 4 16B-slots/row, swizzle slot^=(row&3)^((row>>2)&3)
// (2 lanes/bank on frag reads = free). Staging: linear gl16 dest + pre-swizzled source.
#define GEMM_PIPE(APTR, BPTR, ACC) do { \
    int bc_ = 0, bs_ = 2; \
    STAGE(0, 0); STAGE(1, 1); \
    for (int it_ = 0; it_ < 16; ++it_) { \
        asm volatile("" ::: "memory"); \
        __builtin_amdgcn_s_barrier();                /* compute(it-1) done -> buf bs_ free */ \
        if (it_ + 2 < 16) { \
            STAGE(it_ + 2, bs_); \
            asm volatile("s_waitcnt vmcnt(8)" ::: "memory");   /* tile it landed */ \
        } else if (it_ + 1 < 16) { \
            asm volatile("s_waitcnt vmcnt(4)" ::: "memory"); \
        } else { \
            asm volatile("s_waitcnt vmcnt(0)" ::: "memory"); \
        } \
        __builtin_amdgcn_s_barrier();                /* tile it visible to all waves */ \
        asm volatile("" ::: "memory"); \
        const char* Ab_ = (const char*)(APTR) + bc_ * 8192; \
        const char* Bb_ = (const char*)(BPTR) + bc_ * 8192; \
        s16x8 af_[4], bf_[4]; \
        _Pragma("unroll") \
        for (int i_ = 0; i_ < 4; ++i_) { \
            af_[i_] = *(const s16x8*)(Ab_ + (wm * 64 + i_ * 16 + l15) * 64 + swz); \
            bf_[i_] = *(const s16x8*)(Bb_ + (wn * 64 + i_ * 16 + l15) * 64 + swz); \
        } \
        __builtin_amdgcn_s_setprio(1); \
        _Pragma("unroll") \
        for (int i_ = 0; i_ < 4; ++i_) \
            _Pragma("unroll") \
            for (int j_ = 0; j_ < 4; ++j_) \
                ACC[i_][j_] = __builtin_amdgcn_mfma_f32_16x16x32_bf16(af_[i_], bf_[j_], ACC[i_][j_], 0, 0, 0); \
        __builtin_amdgcn_s_setprio(0); \
        bc_ = (bc_ == 2) ? 0 : bc_ + 1; \
        bs_ = (bs_ == 2) ? 0 : bs_ + 1; \
    } \
} while (0)

// ---------------- QKV projection GEMM ----------------
// z=0 -> q (b,h,s,dk) scaled 0.125*log2e ; z=1 -> k (b,h,s,dk) ; z=2 -> v^T (b,h,dk,s)
__global__ __launch_bounds__(256, 3) void qkv_kernel(const unsigned short* __restrict__ xn,
        const unsigned short* __restrict__ wbase,
        const float* __restrict__ bq, const float* __restrict__ bk, const float* __restrict__ bv,
        unsigned short* __restrict__ qo, unsigned short* __restrict__ ko,
        unsigned short* __restrict__ vt)
{
    __shared__ __align__(16) unsigned short As[3][128 * 32];   // 24KB
    __shared__ __align__(16) unsigned short Bs[3][128 * 32];   // 24KB
    int z = blockIdx.z;
    const unsigned short* W = wbase + (size_t)z * 262144;
    const float* bias = (z == 0) ? bq : (z == 1) ? bk : bv;

    int t = threadIdx.x, lane = t & 63, w = t >> 6;
    int g = lane >> 4, l15 = lane & 15;
    int wm = w >> 1, wn = w & 1;
    int mBase = blockIdx.x * 128, nBase = blockIdx.y * 128;

    // staging: thread t covers rows srow, srow+64; pre-swizzled source col
    int srow = t >> 2;
    int scol = ((t & 3) ^ ((t >> 2) & 3) ^ ((t >> 4) & 3)) * 8;
    const unsigned short* ag = xn + (size_t)(mBase + srow) * 512 + scol;
    const unsigned short* bg = W + (size_t)(nBase + srow) * 512 + scol;
    // fragment-read swizzle (loop-invariant)
    int swz = ((g ^ (l15 & 3) ^ ((l15 >> 2) & 3))) * 16;

    f32x4 acc[4][4] = {};

#define STAGE(it_, buf_) do { \
        int k0_ = (it_) * 32; \
        gl16(ag + k0_,          (char*)&As[buf_][0] + t * 16); \
        gl16(ag + 32768 + k0_,  (char*)&As[buf_][0] + t * 16 + 4096); \
        gl16(bg + k0_,          (char*)&Bs[buf_][0] + t * 16); \
        gl16(bg + 32768 + k0_,  (char*)&Bs[buf_][0] + t * 16 + 4096); \
    } while (0)

    GEMM_PIPE(&As[0][0], &Bs[0][0], acc);
#undef STAGE

#pragma unroll
    for (int i = 0; i < 4; ++i) {
        int row0 = mBase + wm * 64 + i * 16 + g * 4;
        int bb = row0 >> 11;
        int s0 = row0 & 2047;
#pragma unroll
        for (int j = 0; j < 4; ++j) {
            int col = nBase + wn * 64 + j * 16 + l15;
            float bia = bias[col];
            int h = col >> 6, dk = col & 63;
            if (z == 2) {
                s16x4 pk;
#pragma unroll
                for (int r = 0; r < 4; ++r) pk[r] = f2bf(acc[i][j][r] + bia);
                *(s16x4*)(vt + ((size_t)(bb * 8 + h) * 64 + dk) * 2048 + s0) = pk;
            } else {
                unsigned short* dst = (z == 0) ? qo : ko;
                float sc = (z == 0) ? 0.18033688011112042f : 1.0f;   // 0.125*log2(e)
#pragma unroll
                for (int r = 0; r < 4; ++r)
                    dst[((size_t)(bb * 8 + h) * 2048 + (s0 + r)) * 64 + dk] = f2bf((acc[i][j][r] + bia) * sc);
            }
        }
    }
}

// ---------------- flash attention, KV-split-2, fp32 linear partials ----------------
__global__ __launch_bounds__(256, 4) void attn_kernel(const unsigned short* __restrict__ q,
        const unsigned short* __restrict__ k, const unsigned short* __restrict__ vt,
        const int* __restrict__ lens, float* __restrict__ o_part, float* __restrict__ l_part)
{
    __shared__ __align__(16) unsigned short Ks[2][4096];    // [buf][64k x 64dk] 8KB
    __shared__ __align__(16) unsigned short Vts[2][4096];   // [buf][64dk x 64s] 8KB

    int t = threadIdx.x, lane = t & 63, w = t >> 6;
    int g = lane >> 4, l15 = lane & 15;
    int lin = blockIdx.x;
    int bh = lin & 31;
    int rest = lin >> 5;               // 0..31
    int split = rest & 1;
    int qt = rest >> 1;                // 0..15
    int b = bh >> 3, h = bh & 7;
    int qb = qt * 128 + w * 32;
    int len = lens[b];
    int ntf = (len + 63) >> 6;
    int nt0 = (ntf + 1) >> 1;
    int tbeg = split ? nt0 : 0;
    int ntX = (split ? ntf : nt0) - tbeg;

    const unsigned short* kbh = k + (size_t)bh * 131072;
    const unsigned short* vbh = vt + (size_t)bh * 131072;

    s16x8 qf_[2][2];
#pragma unroll
    for (int qf = 0; qf < 2; ++qf)
#pragma unroll
        for (int ks = 0; ks < 2; ++ks)
            qf_[qf][ks] = *(const s16x8*)(q + ((size_t)bh * 2048 + qb + qf * 16 + l15) * 64 + ks * 32 + g * 8);

    int cr = t >> 3;                       // 0..31
    int cc = ((t & 7) ^ (cr & 7)) * 8;     // pre-swizzled source col
    const unsigned short* kgp = kbh + cr * 64 + cc;
    const unsigned short* vgp = vbh + (size_t)cr * 2048 + cc;

    s16x8 ones;
#pragma unroll
    for (int i = 0; i < 8; ++i) ones[i] = (short)0x3F80;   // bf16 1.0

    f32x4 oacc[2][4] = {};   // [qf][nf]
    f32x4 sacc[2] = {};

#define STAGE(tile, buf) do { \
        const unsigned short* kp_ = kgp + (size_t)(tile) * 4096; \
        const unsigned short* vp_ = vgp + (tile) * 64; \
        char* kld_ = (char*)&Ks[buf][0] + t * 16; \
        char* vld_ = (char*)&Vts[buf][0] + t * 16; \
        gl16(kp_, kld_);          gl16(kp_ + 2048, kld_ + 4096); \
        gl16(vp_, vld_);          gl16(vp_ + 65536, vld_ + 4096); \
    } while (0)

    STAGE(tbeg, 0);

    for (int li = 0; li < ntX; ++li) {
        int tt = tbeg + li;
        int kb = tt << 6;
        asm volatile("" ::: "memory");
        __builtin_amdgcn_s_barrier();
        if (li + 1 < ntX) {
            STAGE(tt + 1, (li + 1) & 1);
            asm volatile("s_waitcnt vmcnt(4)" ::: "memory");
        } else {
            asm volatile("s_waitcnt vmcnt(0)" ::: "memory");
        }
        __builtin_amdgcn_s_barrier();
        asm volatile("" ::: "memory");

        const char* Kb = (const char*)&Ks[li & 1][0];
        const char* Vb = (const char*)&Vts[li & 1][0];

        f32x4 sa[4][2] = {};
#pragma unroll
        for (int ks = 0; ks < 2; ++ks) {
            s16x8 ka[4];
#pragma unroll
            for (int kf = 0; kf < 4; ++kf) {
                int kr = kf * 16 + l15;
                ka[kf] = *(const s16x8*)(Kb + kr * 128 + ((ks * 64 + g * 16) ^ ((kr & 7) << 4)));
            }
            __builtin_amdgcn_s_setprio(1);
#pragma unroll
            for (int kf = 0; kf < 4; ++kf)
#pragma unroll
                for (int qf = 0; qf < 2; ++qf)
                    sa[kf][qf] = __builtin_amdgcn_mfma_f32_16x16x32_bf16(ka[kf], qf_[qf][ks], sa[kf][qf], 0, 0, 0);
            __builtin_amdgcn_s_setprio(0);
        }

        if (kb + 64 > len) {
            const float NEG = -__builtin_huge_valf();
#pragma unroll
            for (int kf = 0; kf < 4; ++kf)
#pragma unroll
                for (int r = 0; r < 4; ++r)
                    if (kb + kf * 16 + g * 4 + r >= len) { sa[kf][0][r] = NEG; sa[kf][1][r] = NEG; }
        }

#pragma unroll
        for (int half = 0; half < 2; ++half) {
            s16x8 vbf[4];
#pragma unroll
            for (int nf = 0; nf < 4; ++nf) {
                int dr = nf * 16 + l15;
                vbf[nf] = *(const s16x8*)(Vb + dr * 128 + ((half * 64 + g * 16) ^ ((dr & 7) << 4)));
            }
            u32 pkd[2][2][2];
#pragma unroll
            for (int qf = 0; qf < 2; ++qf)
#pragma unroll
                for (int k2 = 0; k2 < 2; ++k2) {
                    int kf = half * 2 + k2;
#pragma unroll
                    for (int r = 0; r < 4; ++r)
                        sa[kf][qf][r] = __builtin_amdgcn_exp2f(sa[kf][qf][r]);
                    pkd[k2][qf][0] = cvtpk(sa[kf][qf][0], sa[kf][qf][1]);
                    pkd[k2][qf][1] = cvtpk(sa[kf][qf][2], sa[kf][qf][3]);
                }
            __builtin_amdgcn_s_setprio(1);
#pragma unroll
            for (int qf = 0; qf < 2; ++qf) {
                u32 a0 = pkd[0][qf][0], b0 = pkd[1][qf][0];
                u32 a1 = pkd[0][qf][1], b1 = pkd[1][qf][1];
                pl32swap(a0, b0); pl16swap(a0, b0);
                pl32swap(a1, b1); pl16swap(a1, b1);
                union { u32 d[4]; s16x8 v; } pf;
                pf.d[0] = a0; pf.d[1] = a1; pf.d[2] = b0; pf.d[3] = b1;
                sacc[qf] = __builtin_amdgcn_mfma_f32_16x16x32_bf16(pf.v, ones, sacc[qf], 0, 0, 0);
#pragma unroll
                for (int nf = 0; nf < 4; ++nf)
                    oacc[qf][nf] = __builtin_amdgcn_mfma_f32_16x16x32_bf16(pf.v, vbf[nf], oacc[qf][nf], 0, 0, 0);
            }
            __builtin_amdgcn_s_setprio(0);
        }
        asm volatile("" ::: "memory");
    }
#undef STAGE

    float* op = o_part + (size_t)split * (8192 * 512);
#pragma unroll
    for (int qf = 0; qf < 2; ++qf)
#pragma unroll
        for (int r = 0; r < 4; ++r) {
            int s = qb + qf * 16 + g * 4 + r;
#pragma unroll
            for (int nf = 0; nf < 4; ++nf)
                op[(size_t)(b * 2048 + s) * 512 + h * 64 + nf * 16 + l15] = oacc[qf][nf][r];
        }
    float* lp = l_part + split * 65536 + bh * 2048;
    if (l15 == 0) {
#pragma unroll
        for (int qf = 0; qf < 2; ++qf)
#pragma unroll
            for (int r = 0; r < 4; ++r)
                lp[qb + qf * 16 + g * 4 + r] = sacc[qf][r];
    }
}

// ---------------- combine: (O0+O1)/(l0+l1) -> bf16 ----------------
__global__ __launch_bounds__(256) void comb_kernel(const float* __restrict__ o_part,
        const float* __restrict__ l_part, unsigned short* __restrict__ A)
{
    int t = threadIdx.x;
    int row = blockIdx.x * 2 + (t >> 7);
    int cq = t & 127;
    int b = row >> 11, s = row & 2047, h = cq >> 4;
    const f32x4* o4 = (const f32x4*)o_part;
    f32x4 a = o4[(size_t)row * 128 + cq];
    f32x4 c = o4[(size_t)(8192 + row) * 128 + cq];
    float l = l_part[(b * 8 + h) * 2048 + s] + l_part[65536 + (b * 8 + h) * 2048 + s];
    float inv = 1.f / l;
    s16x4 o;
#pragma unroll
    for (int i = 0; i < 4; ++i) o[i] = f2bf((a[i] + c[i]) * inv);
    *(s16x4*)(A + (size_t)row * 512 + cq * 4) = o;
}

// ---------------- output projection GEMM (fp32 out) ----------------
__global__ __launch_bounds__(256, 3) void oproj_kernel(const unsigned short* __restrict__ A,
        const unsigned short* __restrict__ W, const float* __restrict__ bo,
        float* __restrict__ out)
{
    __shared__ __align__(16) unsigned short As[3][128 * 32];
    __shared__ __align__(16) unsigned short Bs[3][128 * 32];
    int t = threadIdx.x, lane = t & 63, w = t >> 6;
    int g = lane >> 4, l15 = lane & 15;
    int wm = w >> 1, wn = w & 1;
    int mBase = blockIdx.x * 128, nBase = blockIdx.y * 128;

    int srow = t >> 2;
    int scol = ((t & 3) ^ ((t >> 2) & 3) ^ ((t >> 4) & 3)) * 8;
    const unsigned short* ag = A + (size_t)(mBase + srow) * 512 + scol;
    const unsigned short* bg = W + (size_t)(nBase + srow) * 512 + scol;
    int swz = ((g ^ (l15 & 3) ^ ((l15 >> 2) & 3))) * 16;

    f32x4 acc[4][4] = {};

#define STAGE(it_, buf_) do { \
        int k0_ = (it_) * 32; \
        gl16(ag + k0_,          (char*)&As[buf_][0] + t * 16); \
        gl16(ag + 32768 + k0_,  (char*)&As[buf_][0] + t * 16 + 4096); \
        gl16(bg + k0_,          (char*)&Bs[buf_][0] + t * 16); \
        gl16(bg + 32768 + k0_,  (char*)&Bs[buf_][0] + t * 16 + 4096); \
    } while (0)

    GEMM_PIPE(&As[0][0], &Bs[0][0], acc);
#undef STAGE

#pragma unroll
    for (int i = 0; i < 4; ++i) {
        int row0 = mBase + wm * 64 + i * 16 + g * 4;
#pragma unroll
        for (int j = 0; j < 4; ++j) {
            int col = nBase + wn * 64 + j * 16 + l15;
            float bia = bo[col];
#pragma unroll
            for (int r = 0; r < 4; ++r)
                out[(size_t)(row0 + r) * 512 + col] = acc[i][j][r] + bia;
        }
    }
}

extern "C" void kernel_launch(void* const* d_in, const int* in_sizes, int n_in,
                              void* d_out, int out_size, void* d_ws, size_t ws_size,
                              hipStream_t stream) {
    (void)in_sizes; (void)n_in; (void)out_size; (void)ws_size;
    const float* x     = (const float*)d_in[0];
    const int*   lens  = (const int*)d_in[1];
    // d_in[2] = pos_embed (unused by reference)
    const float* gamma = (const float*)d_in[3];
    const float* beta  = (const float*)d_in[4];
    const float* Wq = (const float*)d_in[5];
    const float* bq = (const float*)d_in[6];
    const float* Wk = (const float*)d_in[7];
    const float* bk = (const float*)d_in[8];
    const float* Wv = (const float*)d_in[9];
    const float* bv = (const float*)d_in[10];
    const float* Wo = (const float*)d_in[11];
    const float* bo = (const float*)d_in[12];

    char* ws = (char*)d_ws;
    unsigned short* wbf = (unsigned short*)(ws);                  // 0..2MB: 4x512x512 bf16
    unsigned short* xn  = (unsigned short*)(ws + (2ull  << 20));  // 2..10MB: LN out / attn-combined (oproj A)
    unsigned short* qb_ = (unsigned short*)(ws + (10ull << 20));  // (b,h,s,dk)
    unsigned short* kb_ = (unsigned short*)(ws + (18ull << 20));  // (b,h,s,dk)
    unsigned short* vtb = (unsigned short*)(ws + (26ull << 20));  // (b,h,dk,s)
    float* o_part = (float*)(ws + (34ull << 20));                 // 34..66MB: [2][8192][512] f32
    float* l_part = (float*)(ws + (66ull << 20));                 // 66..66.5MB: [2][32][2048] f32
    float* out = (float*)d_out;

    lnw_kernel<<<2304, 256, 0, stream>>>(x, gamma, beta, xn, Wq, Wk, Wv, Wo, wbf);
    qkv_kernel<<<dim3(64, 4, 3), 256, 0, stream>>>(xn, wbf, bq, bk, bv, qb_, kb_, vtb);
    attn_kernel<<<1024, 256, 0, stream>>>(qb_, kb_, vtb, lens, o_part, l_part);
    comb_kernel<<<4096, 256, 0, stream>>>(o_part, l_part, xn);
    oproj_kernel<<<dim3(64, 4), 256, 0, stream>>>(xn, wbf + 3 * 262144, bo, out);
}

// Round 9
// 89.721 us; speedup vs baseline: 1.8911x; 1.0252x over previous
//
#include <hip/hip_runtime.h>

typedef short s16x4 __attribute__((ext_vector_type(4)));
typedef short s16x8 __attribute__((ext_vector_type(8)));
typedef float f32x4 __attribute__((ext_vector_type(4)));
typedef unsigned int u32;

#define DEV static __device__ __forceinline__

// B=4, S=2048, D=512, H=8, DK=64, M = B*S = 8192

DEV unsigned short f2bf(float f) {
    unsigned u = __float_as_uint(f);
    u += 0x7FFFu + ((u >> 16) & 1u);   // RNE round to bf16
    return (unsigned short)(u >> 16);
}

DEV u32 cvtpk(float lo, float hi) {
    u32 r;
    asm("v_cvt_pk_bf16_f32 %0, %1, %2" : "=v"(r) : "v"(lo), "v"(hi));
    return r;
}
DEV void pl32swap(u32& a, u32& b) {
    asm("v_permlane32_swap_b32 %0, %1" : "+v"(a), "+v"(b));
}
DEV void pl16swap(u32& a, u32& b) {
    asm("v_permlane16_swap_b32 %0, %1" : "+v"(a), "+v"(b));
}
DEV void gl16(const void* g, void* l) {
    __builtin_amdgcn_global_load_lds((const __attribute__((address_space(1))) u32*)g,
                                     (__attribute__((address_space(3))) u32*)l, 16, 0, 0);
}

// ---------------- fused LayerNorm + weight convert ----------------
__global__ __launch_bounds__(256) void lnw_kernel(const float* __restrict__ x,
        const float* __restrict__ gamma, const float* __restrict__ beta,
        unsigned short* __restrict__ xn,
        const float* __restrict__ wq, const float* __restrict__ wk,
        const float* __restrict__ wv, const float* __restrict__ wo,
        unsigned short* __restrict__ wdst)
{
    if (blockIdx.x >= 2048) {
        int idx = blockIdx.x - 2048;
        int m = idx >> 6, sub = idx & 63;
        const float* src = (m == 0) ? wq : (m == 1) ? wk : (m == 2) ? wv : wo;
        unsigned short* d = wdst + (size_t)m * 262144;
        const f32x4* s4 = (const f32x4*)src;
        s16x4* d4 = (s16x4*)d;
#pragma unroll
        for (int i = 0; i < 4; ++i) {
            int e = sub * 1024 + i * 256 + threadIdx.x;
            f32x4 v = s4[e];
            s16x4 o;
            o[0] = f2bf(v[0]); o[1] = f2bf(v[1]); o[2] = f2bf(v[2]); o[3] = f2bf(v[3]);
            d4[e] = o;
        }
        return;
    }
    int t = threadIdx.x, w = t >> 6, lane = t & 63;
    int row = blockIdx.x * 4 + w;
    const float* xr = x + (size_t)row * 512 + lane * 8;
    f32x4 v0 = *(const f32x4*)xr;
    f32x4 v1 = *(const f32x4*)(xr + 4);
    float s = 0.f, s2 = 0.f;
#pragma unroll
    for (int i = 0; i < 4; ++i) { s += v0[i] + v1[i]; s2 += v0[i] * v0[i] + v1[i] * v1[i]; }
#pragma unroll
    for (int m = 1; m < 64; m <<= 1) { s += __shfl_xor(s, m); s2 += __shfl_xor(s2, m); }
    float mu = s * (1.f / 512.f);
    float var = s2 * (1.f / 512.f) - mu * mu;
    float rstd = rsqrtf(var + 1e-5f);
    f32x4 g0 = *(const f32x4*)(gamma + lane * 8);
    f32x4 g1 = *(const f32x4*)(gamma + lane * 8 + 4);
    f32x4 b0 = *(const f32x4*)(beta + lane * 8);
    f32x4 b1 = *(const f32x4*)(beta + lane * 8 + 4);
    s16x8 o;
#pragma unroll
    for (int i = 0; i < 4; ++i) {
        o[i]     = f2bf((v0[i] - mu) * rstd * g0[i] + b0[i]);
        o[i + 4] = f2bf((v1[i] - mu) * rstd * g1[i] + b1[i]);
    }
    *(s16x8*)(xn + (size_t)row * 512 + lane * 8) = o;
}

// ---------------- pipelined 128x128 GEMM core (BK=32, 3-buf, depth-2 prefetch) ----------------
#define GEMM_PIPE(APTR, BPTR, ACC) do { \
    int bc_ = 0, bs_ = 2; \
    STAGE(0, 0); STAGE(1, 1); \
    for (int it_ = 0; it_ < 16; ++it_) { \
        asm volatile("" ::: "memory"); \
        __builtin_amdgcn_s_barrier(); \
        if (it_ + 2 < 16) { \
            STAGE(it_ + 2, bs_); \
            asm volatile("s_waitcnt vmcnt(8)" ::: "memory"); \
        } else if (it_ + 1 < 16) { \
            asm volatile("s_waitcnt vmcnt(4)" ::: "memory"); \
        } else { \
            asm volatile("s_waitcnt vmcnt(0)" ::: "memory"); \
        } \
        __builtin_amdgcn_s_barrier(); \
        asm volatile("" ::: "memory"); \
        const char* Ab_ = (const char*)(APTR) + bc_ * 8192; \
        const char* Bb_ = (const char*)(BPTR) + bc_ * 8192; \
        s16x8 af_[4], bf_[4]; \
        _Pragma("unroll") \
        for (int i_ = 0; i_ < 4; ++i_) { \
            af_[i_] = *(const s16x8*)(Ab_ + (wm * 64 + i_ * 16 + l15) * 64 + swz); \
            bf_[i_] = *(const s16x8*)(Bb_ + (wn * 64 + i_ * 16 + l15) * 64 + swz); \
        } \
        __builtin_amdgcn_s_setprio(1); \
        _Pragma("unroll") \
        for (int i_ = 0; i_ < 4; ++i_) \
            _Pragma("unroll") \
            for (int j_ = 0; j_ < 4; ++j_) \
                ACC[i_][j_] = __builtin_amdgcn_mfma_f32_16x16x32_bf16(af_[i_], bf_[j_], ACC[i_][j_], 0, 0, 0); \
        __builtin_amdgcn_s_setprio(0); \
        bc_ = (bc_ == 2) ? 0 : bc_ + 1; \
        bs_ = (bs_ == 2) ? 0 : bs_ + 1; \
    } \
} while (0)

// ---------------- QKV projection GEMM ----------------
// z=0 -> q (b,h,s,dk) scaled 0.125*log2e ; z=1 -> K frag-major ; z=2 -> V frag-major
// frag-major: elem K[s][dk] at ((bh*32+tile)*8 + kf*2+ks)*512 + (g*16+l15)*8 + e
//   tile=s>>6, kf=(s>>4)&3, l15=s&15, ks=dk>>5, g=(dk>>3)&3, e=dk&7
// V[s][dk] (as V^T frags): ((bh*32+tile)*8 + nf*2+half)*512 + (g*16+l15v)*8 + e
//   nf=dk>>4, l15v=dk&15, half=(s>>5)&1, g=(s>>3)&3, e=s&7
__global__ __launch_bounds__(256, 3) void qkv_kernel(const unsigned short* __restrict__ xn,
        const unsigned short* __restrict__ wbase,
        const float* __restrict__ bq, const float* __restrict__ bk, const float* __restrict__ bv,
        unsigned short* __restrict__ qo, unsigned short* __restrict__ kfm,
        unsigned short* __restrict__ vfm)
{
    __shared__ __align__(16) unsigned short As[3][128 * 32];
    __shared__ __align__(16) unsigned short Bs[3][128 * 32];
    int z = blockIdx.z;
    const unsigned short* W = wbase + (size_t)z * 262144;
    const float* bias = (z == 0) ? bq : (z == 1) ? bk : bv;

    int t = threadIdx.x, lane = t & 63, w = t >> 6;
    int g = lane >> 4, l15 = lane & 15;
    int wm = w >> 1, wn = w & 1;
    int mBase = blockIdx.x * 128, nBase = blockIdx.y * 128;

    int srow = t >> 2;
    int scol = ((t & 3) ^ ((t >> 2) & 3) ^ ((t >> 4) & 3)) * 8;
    const unsigned short* ag = xn + (size_t)(mBase + srow) * 512 + scol;
    const unsigned short* bg = W + (size_t)(nBase + srow) * 512 + scol;
    int swz = ((g ^ (l15 & 3) ^ ((l15 >> 2) & 3))) * 16;

    f32x4 acc[4][4] = {};

#define STAGE(it_, buf_) do { \
        int k0_ = (it_) * 32; \
        gl16(ag + k0_,          (char*)&As[buf_][0] + t * 16); \
        gl16(ag + 32768 + k0_,  (char*)&As[buf_][0] + t * 16 + 4096); \
        gl16(bg + k0_,          (char*)&Bs[buf_][0] + t * 16); \
        gl16(bg + 32768 + k0_,  (char*)&Bs[buf_][0] + t * 16 + 4096); \
    } while (0)

    GEMM_PIPE(&As[0][0], &Bs[0][0], acc);
#undef STAGE

#pragma unroll
    for (int i = 0; i < 4; ++i) {
        int row0 = mBase + wm * 64 + i * 16 + g * 4;
        int bb = row0 >> 11;
        int s0 = row0 & 2047;
#pragma unroll
        for (int j = 0; j < 4; ++j) {
            int col = nBase + wn * 64 + j * 16 + l15;
            float bia = bias[col];
            int h = col >> 6, dk = col & 63;
            int bh = bb * 8 + h;
            if (z == 0) {
                float sc = 0.18033688011112042f;   // 0.125*log2(e)
#pragma unroll
                for (int r = 0; r < 4; ++r)
                    qo[((size_t)bh * 2048 + (s0 + r)) * 64 + dk] = f2bf((acc[i][j][r] + bia) * sc);
            } else if (z == 1) {
                int ks = dk >> 5, gg = (dk >> 3) & 3, e = dk & 7;
                int tile = s0 >> 6, kf = (s0 >> 4) & 3, l0 = s0 & 15;
                size_t base = ((size_t)bh * 32 + tile) * 4096 + (kf * 2 + ks) * 512 + (gg * 16 + l0) * 8 + e;
#pragma unroll
                for (int r = 0; r < 4; ++r)
                    kfm[base + r * 8] = f2bf(acc[i][j][r] + bia);
            } else {
                int nf = dk >> 4, l0v = dk & 15;
                int tile = s0 >> 6, half = (s0 >> 5) & 1, gg = (s0 >> 3) & 3, e0 = s0 & 7;
                size_t base = ((size_t)bh * 32 + tile) * 4096 + (nf * 2 + half) * 512 + (gg * 16 + l0v) * 8 + e0;
                s16x4 pk;
#pragma unroll
                for (int r = 0; r < 4; ++r) pk[r] = f2bf(acc[i][j][r] + bia);
                *(s16x4*)(vfm + base) = pk;
            }
        }
    }
}

// ---------------- flash attention: K from global (frag-major), V-only LDS, 1 barrier/tile ----------------
// grid 1024, 256 thr = 4 waves x 32 q (128 q/block), KV-split-2.
// V LDS: 4 bufs x 8KB = 32KB, stage t+2 pre-barrier (bufs {t-1,t,t+1,t+2} distinct mod 4).
// counted vmcnt certifies V(t); single barrier gives cross-wave visibility.
__global__ __launch_bounds__(256, 4) void attn_kernel(const unsigned short* __restrict__ q,
        const unsigned short* __restrict__ kfm, const unsigned short* __restrict__ vfm,
        const int* __restrict__ lens, unsigned short* __restrict__ o_part, float* __restrict__ l_part)
{
    __shared__ __align__(16) unsigned short Vts[4][4096];   // [buf][8 frags][512 elems]

    int t = threadIdx.x, lane = t & 63, w = t >> 6;
    int g = lane >> 4, l15 = lane & 15;
    int lin = blockIdx.x;
    int bh = lin & 31;
    int rest = lin >> 5;               // 0..31
    int split = rest & 1;
    int qt = rest >> 1;                // 0..15
    int b = bh >> 3, h = bh & 7;
    int qb = qt * 128 + w * 32;
    int len = lens[b];
    int ntf = (len + 63) >> 6;
    int nt0 = (ntf + 1) >> 1;
    int tbeg = split ? nt0 : 0;
    int ntX = (split ? ntf : nt0) - tbeg;

    const unsigned short* kbh = kfm + (size_t)bh * 131072;
    const unsigned short* vbh = vfm + (size_t)bh * 131072;

    s16x8 qf_[2][2];
#pragma unroll
    for (int qf = 0; qf < 2; ++qf)
#pragma unroll
        for (int ks = 0; ks < 2; ++ks)
            qf_[qf][ks] = *(const s16x8*)(q + ((size_t)bh * 2048 + qb + qf * 16 + l15) * 64 + ks * 32 + g * 8);

    s16x8 ones;
#pragma unroll
    for (int i = 0; i < 8; ++i) ones[i] = (short)0x3F80;   // bf16 1.0

    f32x4 oacc[2][4] = {};   // [qf][nf]
    f32x4 sacc[2] = {};

#define STAGE_V(tile, buf) do { \
        const unsigned short* vp_ = vbh + (size_t)(tile) * 4096 + t * 8; \
        char* vld_ = (char*)&Vts[buf][0] + t * 16; \
        gl16(vp_, vld_); \
        gl16(vp_ + 2048, vld_ + 4096); \
    } while (0)

    STAGE_V(tbeg, 0);
    if (ntX > 1) STAGE_V(tbeg + 1, 1);

    for (int li = 0; li < ntX; ++li) {
        int tt = tbeg + li;
        int kb = tt << 6;

        // K fragments straight from global (coalesced 1KB per load, L2/L1-resident)
        const unsigned short* kt = kbh + (size_t)tt * 4096;
        s16x8 ka[4][2];
#pragma unroll
        for (int kf = 0; kf < 4; ++kf)
#pragma unroll
            for (int ks = 0; ks < 2; ++ks)
                ka[kf][ks] = *(const s16x8*)(kt + ((kf & 1) * 2 + ks) * 512 + (kf >> 1) * 2048 + lane * 8);

        if (li + 2 < ntX) {
            STAGE_V(tt + 2, (li + 2) & 3);
            asm volatile("s_waitcnt vmcnt(12)" ::: "memory");   // V(li) landed; V(li+1),ka,V(li+2) in flight
        } else if (li + 1 < ntX) {
            asm volatile("s_waitcnt vmcnt(10)" ::: "memory");   // leaves V(li+1)+ka
        } else {
            asm volatile("s_waitcnt vmcnt(8)" ::: "memory");    // leaves ka only
        }
        __builtin_amdgcn_s_barrier();              // all waves certified V(li)
        asm volatile("" ::: "memory");

        const char* Vb = (const char*)&Vts[li & 3][0];

        // QK^T -> S^T: sa[kf2][qf] where k-row = kf2*16 + g*4 + r  (kf2 = frag index 0..3)
        f32x4 sa[4][2] = {};
#pragma unroll
        for (int ks = 0; ks < 2; ++ks) {
            __builtin_amdgcn_s_setprio(1);
#pragma unroll
            for (int kf = 0; kf < 4; ++kf)
#pragma unroll
                for (int qf = 0; qf < 2; ++qf)
                    sa[kf][qf] = __builtin_amdgcn_mfma_f32_16x16x32_bf16(
                        ka[(kf >> 1) * 2 + (kf & 1)][ks], qf_[qf][ks], sa[kf][qf], 0, 0, 0);
            __builtin_amdgcn_s_setprio(0);
        }

        if (kb + 64 > len) {
            const float NEG = -__builtin_huge_valf();
#pragma unroll
            for (int kf = 0; kf < 4; ++kf)
#pragma unroll
                for (int r = 0; r < 4; ++r)
                    if (kb + kf * 16 + g * 4 + r >= len) { sa[kf][0][r] = NEG; sa[kf][1][r] = NEG; }
        }

        // two k-halves: exp2 (fixed-max, scale folded into q) -> permlane P -> PV
#pragma unroll
        for (int half = 0; half < 2; ++half) {
            s16x8 vbf[4];
#pragma unroll
            for (int nf = 0; nf < 4; ++nf)
                vbf[nf] = *(const s16x8*)(Vb + (nf * 2 + half) * 1024 + lane * 16);
            u32 pkd[2][2][2];
#pragma unroll
            for (int qf = 0; qf < 2; ++qf)
#pragma unroll
                for (int k2 = 0; k2 < 2; ++k2) {
                    int kf = half * 2 + k2;
#pragma unroll
                    for (int r = 0; r < 4; ++r)
                        sa[kf][qf][r] = __builtin_amdgcn_exp2f(sa[kf][qf][r]);
                    pkd[k2][qf][0] = cvtpk(sa[kf][qf][0], sa[kf][qf][1]);
                    pkd[k2][qf][1] = cvtpk(sa[kf][qf][2], sa[kf][qf][3]);
                }
            __builtin_amdgcn_s_setprio(1);
#pragma unroll
            for (int qf = 0; qf < 2; ++qf) {
                u32 a0 = pkd[0][qf][0], b0 = pkd[1][qf][0];
                u32 a1 = pkd[0][qf][1], b1 = pkd[1][qf][1];
                pl32swap(a0, b0); pl16swap(a0, b0);
                pl32swap(a1, b1); pl16swap(a1, b1);
                union { u32 d[4]; s16x8 v; } pf;
                pf.d[0] = a0; pf.d[1] = a1; pf.d[2] = b0; pf.d[3] = b1;
                sacc[qf] = __builtin_amdgcn_mfma_f32_16x16x32_bf16(pf.v, ones, sacc[qf], 0, 0, 0);
#pragma unroll
                for (int nf = 0; nf < 4; ++nf)
                    oacc[qf][nf] = __builtin_amdgcn_mfma_f32_16x16x32_bf16(pf.v, vbf[nf], oacc[qf][nf], 0, 0, 0);
            }
            __builtin_amdgcn_s_setprio(0);
        }
        asm volatile("" ::: "memory");
    }
#undef STAGE_V

    // write bf16 unnormalized O partial + fp32 l partial
    unsigned short* op = o_part + (size_t)split * (8192 * 512);
#pragma unroll
    for (int qf = 0; qf < 2; ++qf)
#pragma unroll
        for (int r = 0; r < 4; ++r) {
            int s = qb + qf * 16 + g * 4 + r;
#pragma unroll
            for (int nf = 0; nf < 4; ++nf)
                op[(size_t)(b * 2048 + s) * 512 + h * 64 + nf * 16 + l15] = f2bf(oacc[qf][nf][r]);
        }
    float* lp = l_part + split * 65536 + bh * 2048;
    if (l15 == 0) {
#pragma unroll
        for (int qf = 0; qf < 2; ++qf)
#pragma unroll
            for (int r = 0; r < 4; ++r)
                lp[qb + qf * 16 + g * 4 + r] = sacc[qf][r];
    }
}

// ---------------- combine: (O0+O1)/(l0+l1) -> bf16 ----------------
__global__ __launch_bounds__(256) void comb_kernel(const unsigned short* __restrict__ o_part,
        const float* __restrict__ l_part, unsigned short* __restrict__ A)
{
    int e0 = (blockIdx.x * 256 + threadIdx.x) * 8;
    int row = e0 >> 9, col0 = e0 & 511;
    int b = row >> 11, s = row & 2047, h = col0 >> 6;
    s16x8 u0 = *(const s16x8*)(o_part + (size_t)row * 512 + col0);
    s16x8 u1 = *(const s16x8*)(o_part + (size_t)(8192 + row) * 512 + col0);
    float l = l_part[(b * 8 + h) * 2048 + s] + l_part[65536 + (b * 8 + h) * 2048 + s];
    float inv = 1.f / l;
    s16x8 o;
#pragma unroll
    for (int i = 0; i < 8; ++i) {
        float f0 = __uint_as_float(((u32)(unsigned short)u0[i]) << 16);
        float f1 = __uint_as_float(((u32)(unsigned short)u1[i]) << 16);
        o[i] = f2bf((f0 + f1) * inv);
    }
    *(s16x8*)(A + (size_t)row * 512 + col0) = o;
}

// ---------------- output projection GEMM (fp32 out) ----------------
__global__ __launch_bounds__(256, 3) void oproj_kernel(const unsigned short* __restrict__ A,
        const unsigned short* __restrict__ W, const float* __restrict__ bo,
        float* __restrict__ out)
{
    __shared__ __align__(16) unsigned short As[3][128 * 32];
    __shared__ __align__(16) unsigned short Bs[3][128 * 32];
    int t = threadIdx.x, lane = t & 63, w = t >> 6;
    int g = lane >> 4, l15 = lane & 15;
    int wm = w >> 1, wn = w & 1;
    int mBase = blockIdx.x * 128, nBase = blockIdx.y * 128;

    int srow = t >> 2;
    int scol = ((t & 3) ^ ((t >> 2) & 3) ^ ((t >> 4) & 3)) * 8;
    const unsigned short* ag = A + (size_t)(mBase + srow) * 512 + scol;
    const unsigned short* bg = W + (size_t)(nBase + srow) * 512 + scol;
    int swz = ((g ^ (l15 & 3) ^ ((l15 >> 2) & 3))) * 16;

    f32x4 acc[4][4] = {};

#define STAGE(it_, buf_) do { \
        int k0_ = (it_) * 32; \
        gl16(ag + k0_,          (char*)&As[buf_][0] + t * 16); \
        gl16(ag + 32768 + k0_,  (char*)&As[buf_][0] + t * 16 + 4096); \
        gl16(bg + k0_,          (char*)&Bs[buf_][0] + t * 16); \
        gl16(bg + 32768 + k0_,  (char*)&Bs[buf_][0] + t * 16 + 4096); \
    } while (0)

    GEMM_PIPE(&As[0][0], &Bs[0][0], acc);
#undef STAGE

#pragma unroll
    for (int i = 0; i < 4; ++i) {
        int row0 = mBase + wm * 64 + i * 16 + g * 4;
#pragma unroll
        for (int j = 0; j < 4; ++j) {
            int col = nBase + wn * 64 + j * 16 + l15;
            float bia = bo[col];
#pragma unroll
            for (int r = 0; r < 4; ++r)
                out[(size_t)(row0 + r) * 512 + col] = acc[i][j][r] + bia;
        }
    }
}

extern "C" void kernel_launch(void* const* d_in, const int* in_sizes, int n_in,
                              void* d_out, int out_size, void* d_ws, size_t ws_size,
                              hipStream_t stream) {
    (void)in_sizes; (void)n_in; (void)out_size; (void)ws_size;
    const float* x     = (const float*)d_in[0];
    const int*   lens  = (const int*)d_in[1];
    // d_in[2] = pos_embed (unused by reference)
    const float* gamma = (const float*)d_in[3];
    const float* beta  = (const float*)d_in[4];
    const float* Wq = (const float*)d_in[5];
    const float* bq = (const float*)d_in[6];
    const float* Wk = (const float*)d_in[7];
    const float* bk = (const float*)d_in[8];
    const float* Wv = (const float*)d_in[9];
    const float* bv = (const float*)d_in[10];
    const float* Wo = (const float*)d_in[11];
    const float* bo = (const float*)d_in[12];

    char* ws = (char*)d_ws;
    unsigned short* wbf = (unsigned short*)(ws);                  // 0..2MB: 4x512x512 bf16
    unsigned short* xn  = (unsigned short*)(ws + (2ull  << 20));  // 2..10MB: LN out / attn-combined (oproj A)
    unsigned short* qb_ = (unsigned short*)(ws + (10ull << 20));  // (b,h,s,dk)
    unsigned short* kfm = (unsigned short*)(ws + (18ull << 20));  // K frag-major
    unsigned short* vfm = (unsigned short*)(ws + (26ull << 20));  // V frag-major
    unsigned short* o_part = (unsigned short*)(ws + (34ull << 20)); // 34..50MB: [2][8192][512] bf16
    float* l_part = (float*)(ws + (50ull << 20));                 // 50..50.5MB: [2][32][2048] f32
    float* out = (float*)d_out;

    lnw_kernel<<<2304, 256, 0, stream>>>(x, gamma, beta, xn, Wq, Wk, Wv, Wo, wbf);
    qkv_kernel<<<dim3(64, 4, 3), 256, 0, stream>>>(xn, wbf, bq, bk, bv, qb_, kfm, vfm);
    attn_kernel<<<1024, 256, 0, stream>>>(qb_, kfm, vfm, lens, o_part, l_part);
    comb_kernel<<<2048, 256, 0, stream>>>(o_part, l_part, xn);
    oproj_kernel<<<dim3(64, 4), 256, 0, stream>>>(xn, wbf + 3 * 262144, bo, out);
}